// Round 17
// baseline (31.037 us; speedup 1.0000x reference)
//
#include <hip/hip_runtime.h>
#include <math.h>

#define IN_DIM   16
#define CD       7
#define SAMPS    20
#define KFILT    101
#define SIGLEN   140      // CD * SAMPS
#define MCONST   128      // 2^CD

// ws layout (bytes):
//   [0     .. 4096)  : double partials[512]          (atomic relaxed agent)
//   [4096  .. 6144)  : float  GR[8][64]  G replicas  (atomic relaxed agent)
//   [8192  .. 14592) : barrier region — memset each launch:
//       L0[g]  u32 @  8192 + g*256  (g<8)   group arrival counters
//       GS[g]  f64 @ 10240 + g*256  (g<8)   group sums
//       ROOT   u32 @ 12288                  root counter
//       FLAG[r]u32 @ 12544 + r*256  (r<8)   release flags; value = norm bits
//   [16384 .. +4.2MB): float enc[B][8]               (fallback path only)

__device__ __forceinline__ unsigned ld_u32(const void* p) {
    return __hip_atomic_load((const unsigned*)p, __ATOMIC_RELAXED,
                             __HIP_MEMORY_SCOPE_AGENT);
}
__device__ __forceinline__ void st_u32(void* p, unsigned v) {
    __hip_atomic_store((unsigned*)p, v, __ATOMIC_RELAXED,
                       __HIP_MEMORY_SCOPE_AGENT);
}
__device__ __forceinline__ unsigned add_u32(void* p) {
    return __hip_atomic_fetch_add((unsigned*)p, 1u, __ATOMIC_RELAXED,
                                  __HIP_MEMORY_SCOPE_AGENT);
}
__device__ __forceinline__ double ld_f64(const void* p) {
    return __hip_atomic_load((const double*)p, __ATOMIC_RELAXED,
                             __HIP_MEMORY_SCOPE_AGENT);
}
__device__ __forceinline__ void st_f64(void* p, double v) {
    __hip_atomic_store((double*)p, v, __ATOMIC_RELAXED,
                       __HIP_MEMORY_SCOPE_AGENT);
}
__device__ __forceinline__ float ld_f32(const void* p) {
    return __hip_atomic_load((const float*)p, __ATOMIC_RELAXED,
                             __HIP_MEMORY_SCOPE_AGENT);
}
__device__ __forceinline__ void st_f32(void* p, float v) {
    __hip_atomic_store((float*)p, v, __ATOMIC_RELAXED,
                       __HIP_MEMORY_SCOPE_AGENT);
}

// ---------------------------------------------------------------------------
// Fused single kernel (grid = NB <= 512, 2 blocks/CU co-resident).
// Weights/biases read DIRECTLY from global (wave-uniform addresses -> scalar
// pipe), no LDS staging, no initial block barrier.
// ---------------------------------------------------------------------------
__global__ __launch_bounds__(256, 2) void k_fused(
    const float* __restrict__ x,
    const float* __restrict__ We1, const float* __restrict__ be1,
    const float* __restrict__ We2, const float* __restrict__ be2,
    const float* __restrict__ Wd1, const float* __restrict__ bd1,
    const float* __restrict__ Wd2, const float* __restrict__ bd2,
    const float* __restrict__ h_lp, const float* __restrict__ h_ps,
    const float* __restrict__ noise, const int* __restrict__ snr_p,
    char* __restrict__ ws, float* __restrict__ out, int B, int NB)
{
    int t   = threadIdx.x;
    int bid = blockIdx.x;
    int row = bid * 256 + t;

    double* partials = (double*)(ws + 0);
    float*  GR       = (float*) (ws + 4096);
    char*   L0       = ws + 8192;
    char*   GS       = ws + 10240;
    char*   ROOT     = ws + 12288;
    char*   FLAG     = ws + 12544;

    __shared__ float    str[2 * MCONST];
    __shared__ double   wred[4];
    __shared__ float    sG[49];
    __shared__ float    curp[240], nxtp[240];   // [50 pad | 140 | 50 pad]
    __shared__ unsigned sNormBits;
    __shared__ float    ninv;

    // trig table (read only after the grid barrier -> no sync needed here)
    if (t < MCONST) {
        float ph = (float)(2.0 * 3.14159265358979323846 / (double)MCONST) * (float)t;
        str[t]          = cosf(ph);
        str[MCONST + t] = sinf(ph);
    }

    // ---------------- encoder (unconditional, clamped row) ----------------
    int crow = (row < B) ? row : (B - 1);
    const float4* xp = reinterpret_cast<const float4*>(x + (size_t)crow * IN_DIM);
    float4 v0 = xp[0], v1 = xp[1], v2 = xp[2], v3 = xp[3];
    float xr[16] = {v0.x,v0.y,v0.z,v0.w, v1.x,v1.y,v1.z,v1.w,
                    v2.x,v2.y,v2.z,v2.w, v3.x,v3.y,v3.z,v3.w};
    float h[16];
    #pragma unroll
    for (int i = 0; i < 16; ++i) {
        float acc = be1[i];
        #pragma unroll
        for (int j = 0; j < 16; ++j) acc = fmaf(We1[i*16+j], xr[j], acc);
        h[i] = (acc >= 0.f) ? acc : 0.01f * acc;
    }
    float e[CD];
    double ss = 0.0;
    #pragma unroll
    for (int o = 0; o < CD; ++o) {
        float acc = be2[o];
        #pragma unroll
        for (int i = 0; i < 16; ++i) acc = fmaf(We2[o*16+i], h[i], acc);
        e[o] = acc;
        ss += (double)acc * (double)acc;
    }
    if (row >= B) ss = 0.0;

    // wave shfl reduce (f64), one barrier; store partial (wave-0 global store)
    double v = ss;
    #pragma unroll
    for (int off = 32; off > 0; off >>= 1) v += __shfl_down(v, off);
    if ((t & 63) == 0) wred[t >> 6] = v;
    __syncthreads();
    if (t == 0) st_f64(&partials[bid], (wred[0] + wred[1]) + (wred[2] + wred[3]));

    // ---------------- G column (blocks 0..6), f32, -> 8 replicas ----------
    if (bid < CD) {
        if (t < 240) { curp[t] = 0.0f; nxtp[t] = 0.0f; }
        __syncthreads();
        if (t < SIGLEN) {
            int m = t + 50 - SAMPS * bid;    // conv(delta, h_ps) = shifted h_ps
            curp[t + 50] = (m >= 0 && m < KFILT) ? h_ps[m] : 0.0f;
        }
        __syncthreads();
        for (int f = 0; f < 2; ++f) {
            const float* __restrict__ hg = (f == 0) ? h_lp : h_ps;  // uniform -> scalar
            if (t < SIGLEN) {
                float a0 = 0.f, a1 = 0.f;    // 2-way tap split (shorter chain)
                #pragma unroll 4
                for (int m = 0; m <= 50; ++m)    a0 = fmaf(hg[m], curp[t + 100 - m], a0);
                #pragma unroll 4
                for (int m = 51; m < KFILT; ++m) a1 = fmaf(hg[m], curp[t + 100 - m], a1);
                nxtp[t + 50] = a0 + a1;
            }
            __syncthreads();
            if (t < SIGLEN) curp[t + 50] = nxtp[t + 50];
            __syncthreads();
        }
        if (t < CD) {   // wave-0 lanes 0..6: store into all 8 replicas
            float gv = (float)SAMPS * curp[t * SAMPS + 50];
            #pragma unroll
            for (int r = 0; r < 8; ++r)
                st_f32(&GR[r * 64 + t * CD + bid], gv);
        }
    }

    // ---------------- pre-barrier hoisted work ----------------
    // noise prefetched straight into registers; latency hides under barrier
    float nz[CD];
    {
        const float* np0 = noise + (size_t)crow * CD;
        #pragma unroll
        for (int k = 0; k < CD; ++k) nz[k] = np0[k];
    }
    if (t == 1) {
        int iv = *snr_p;
        float sv = (iv >= -1000 && iv <= 1000) ? (float)iv
                                               : *reinterpret_cast<const float*>(snr_p);
        float snr_lin = powf(10.0f, 0.1f * sv);
        ninv = 1.0f / sqrtf((float)(8.0 / 7.0) * snr_lin);  // 1/sqrt(2*rate*snr)
    }

    // ---------------- barrier: tree arrival, wave-parallel reduce,
    //                  flag carries norm bits ----------------
    __syncthreads();          // all waves done; all global stores were wave-0's
    if (t < 64) {
        asm volatile("s_waitcnt vmcnt(0)" ::: "memory");  // wave-0 stores at LLC
        int g       = bid >> 6;
        int gbase   = g << 6;
        int gsize   = (NB - gbase < 64) ? (NB - gbase) : 64;
        int ngroups = (NB + 63) >> 6;

        unsigned aret = 0;
        if (t == 0) aret = add_u32(L0 + (size_t)g * 256);
        aret = __shfl(aret, 0);
        if ((int)aret == gsize - 1) {
            // group-last: WAVE-PARALLEL reduce of this group's partials
            double p = (t < gsize) ? ld_f64(&partials[gbase + t]) : 0.0;
            #pragma unroll
            for (int off = 32; off > 0; off >>= 1) p += __shfl_down(p, off);
            unsigned rret = 0;
            if (t == 0) {
                st_f64(GS + (size_t)g * 256, p);
                asm volatile("s_waitcnt vmcnt(0)" ::: "memory");
                rret = add_u32(ROOT);
            }
            rret = __shfl(rret, 0);
            if ((int)rret == ngroups - 1) {
                // root-last: wave-parallel reduce of group sums -> norm
                double gsv = (t < ngroups) ? ld_f64(GS + (size_t)t * 256) : 0.0;
                #pragma unroll
                for (int off = 32; off > 0; off >>= 1) gsv += __shfl_down(gsv, off);
                unsigned bits = 0;
                if (t == 0) bits = __float_as_uint((float)sqrt(gsv));
                bits = __shfl(bits, 0);
                if (t < 8) st_u32(FLAG + (size_t)t * 256, bits);
            }
        }
        // release: poll own flag replica; its VALUE is the norm
        if (t == 0) {
            unsigned b2;
            while ((b2 = ld_u32(FLAG + (size_t)(bid & 7) * 256)) == 0u)
                __builtin_amdgcn_s_sleep(2);
            sNormBits = b2;
        }
        // after release, G replicas are globally visible: fetch ours
        if (t < 49) sG[t] = ld_f32(&GR[(size_t)(bid & 7) * 64 + t]);
    }
    __syncthreads();
    float sinv = 70.0f / __uint_as_float(sNormBits);

    // ---------------- phase 2 ----------------
    if (row >= B) return;

    float sr[CD], si[CD], sgn[CD], fidx[CD];
    #pragma unroll
    for (int o = 0; o < CD; ++o) {
        float es = e[o] * sinv;                  // enc * (70/||enc||)
        float rv = rintf(es);                    // jnp.round = half-to-even
        int xi = (int)rv;
        sgn[o] = (xi < 0) ? -1.0f : 1.0f;
        int idx = (xi < 0 ? -xi : xi) & (MCONST - 1);   // mod(|xi|, 128)
        fidx[o] = (float)idx;
        sr[o] = str[idx];
        si[o] = str[MCONST + idx];
    }

    const float QSC = 20.37183271576260f;        // 128 / (2*pi)
    float res[CD];
    #pragma unroll
    for (int k = 0; k < CD; ++k) {
        float yr = 0.f, yi = 0.f;
        #pragma unroll
        for (int cc = 0; cc < CD; ++cc) {
            float g = sG[k * CD + cc];
            yr = fmaf(g, sr[cc], yr);
            yi = fmaf(g, si[cc], yi);
        }
        // rotate by conj(transmitted symbol k): ang = phi_idx + atan2(b, a)
        float c = sr[k], s = si[k];
        float a = fmaf(yr, c, yi * s);           // yr*c + yi*s
        float b = fmaf(yi, c, -(yr * s));        // yi*c - yr*s
        float q;
        if (fabsf(b) < 0.25f * a) {              // small-angle & a>0: poly atan
            float u  = b / a;
            float u2 = u * u;
            float w  = fmaf(u2, -0.142857143f, 0.2f);     // -1/7, +1/5
            w        = fmaf(u2, w, -0.333333333f);        // -1/3
            w        = fmaf(u2, w, 1.0f);
            q = fmaf(u * w, QSC, fidx[k]);
        } else {                                 // rare: exact fallback
            q = fmaf(atan2f(b, a), QSC, fidx[k]);
        }
        float r = rintf(q);                      // q in [-64, 191]
        if (r < 0.0f) r += 128.0f;
        else if (r >= 128.0f) r -= 128.0f;       // jnp.mod semantics
        res[k] = fmaf(nz[k], ninv, r * sgn[k]);
    }

    float dd[16];
    #pragma unroll
    for (int i = 0; i < 16; ++i) {
        float acc = bd1[i];
        #pragma unroll
        for (int cc = 0; cc < CD; ++cc) acc = fmaf(Wd1[i*CD+cc], res[cc], acc);
        dd[i] = (acc >= 0.f) ? acc : 0.01f * acc;
    }
    float4* op = reinterpret_cast<float4*>(out + (size_t)row * IN_DIM);
    #pragma unroll
    for (int q4 = 0; q4 < 4; ++q4) {
        float o0[4];
        #pragma unroll
        for (int u = 0; u < 4; ++u) {
            int i = q4 * 4 + u;
            float acc = bd2[i];
            #pragma unroll
            for (int j = 0; j < 16; ++j) acc = fmaf(Wd2[i*16+j], dd[j], acc);
            o0[u] = acc;
        }
        op[q4] = make_float4(o0[0], o0[1], o0[2], o0[3]);
    }
}

// ---------------------------------------------------------------------------
// Fallback 2-kernel path (r14, proven) for NB > 512
// ---------------------------------------------------------------------------
__global__ __launch_bounds__(256) void k1_enc(
    const float* __restrict__ x,
    const float* __restrict__ We1, const float* __restrict__ be1,
    const float* __restrict__ We2, const float* __restrict__ be2,
    const float* __restrict__ h_lp, const float* __restrict__ h_ps,
    float* __restrict__ enc, double* __restrict__ partials,
    float* __restrict__ Gd, int B)
{
    int t = threadIdx.x, bid = blockIdx.x, row = bid * 256 + t;
    __shared__ double wred[4];
    __shared__ float  curp[240], nxtp[240];
    double ss = 0.0;
    if (row < B) {
        const float4* xp = reinterpret_cast<const float4*>(x + (size_t)row * IN_DIM);
        float4 v0 = xp[0], v1 = xp[1], v2 = xp[2], v3 = xp[3];
        float xr[16] = {v0.x,v0.y,v0.z,v0.w, v1.x,v1.y,v1.z,v1.w,
                        v2.x,v2.y,v2.z,v2.w, v3.x,v3.y,v3.z,v3.w};
        float h[16];
        #pragma unroll
        for (int i = 0; i < 16; ++i) {
            float acc = be1[i];
            #pragma unroll
            for (int j = 0; j < 16; ++j) acc = fmaf(We1[i*16+j], xr[j], acc);
            h[i] = (acc >= 0.f) ? acc : 0.01f * acc;
        }
        float e[8];
        #pragma unroll
        for (int o = 0; o < CD; ++o) {
            float acc = be2[o];
            #pragma unroll
            for (int i = 0; i < 16; ++i) acc = fmaf(We2[o*16+i], h[i], acc);
            e[o] = acc; ss += (double)acc * (double)acc;
        }
        e[7] = 0.f;
        float4* ep = reinterpret_cast<float4*>(enc + (size_t)row * 8);
        ep[0] = make_float4(e[0], e[1], e[2], e[3]);
        ep[1] = make_float4(e[4], e[5], e[6], e[7]);
    }
    double v = ss;
    #pragma unroll
    for (int off = 32; off > 0; off >>= 1) v += __shfl_down(v, off);
    if ((t & 63) == 0) wred[t >> 6] = v;
    __syncthreads();
    if (t == 0) partials[bid] = (wred[0] + wred[1]) + (wred[2] + wred[3]);
    if (bid < CD) {
        if (t < 240) { curp[t] = 0.0f; nxtp[t] = 0.0f; }
        __syncthreads();
        if (t < SIGLEN) {
            int m = t + 50 - SAMPS * bid;
            curp[t + 50] = (m >= 0 && m < KFILT) ? h_ps[m] : 0.0f;
        }
        __syncthreads();
        for (int f = 0; f < 2; ++f) {
            const float* __restrict__ hg = (f == 0) ? h_lp : h_ps;
            if (t < SIGLEN) {
                float a0 = 0.f, a1 = 0.f;
                #pragma unroll 4
                for (int m = 0; m <= 50; ++m)    a0 = fmaf(hg[m], curp[t + 100 - m], a0);
                #pragma unroll 4
                for (int m = 51; m < KFILT; ++m) a1 = fmaf(hg[m], curp[t + 100 - m], a1);
                nxtp[t + 50] = a0 + a1;
            }
            __syncthreads();
            if (t < SIGLEN) curp[t + 50] = nxtp[t + 50];
            __syncthreads();
        }
        if (t < CD) Gd[t * CD + bid] = (float)SAMPS * curp[t * SAMPS + 50];
    }
}

__global__ __launch_bounds__(256) void k2_main(
    const float* __restrict__ enc,
    const float* __restrict__ Wd1, const float* __restrict__ bd1,
    const float* __restrict__ Wd2, const float* __restrict__ bd2,
    const float* __restrict__ noise, const int* __restrict__ snr_p,
    const double* __restrict__ partials, const float* __restrict__ Gd,
    float* __restrict__ out, int B, int NBP)
{
    int t = threadIdx.x, bid = blockIdx.x, base_row = bid * 512;
    __shared__ float  str[2 * MCONST];
    __shared__ float  sG[49];
    __shared__ double wred[4];
    __shared__ float  sinv, ninv;
    if (t < 49)  sG[t] = Gd[t];
    if (t < MCONST) {
        float ph = (float)(2.0 * 3.14159265358979323846 / (double)MCONST) * (float)t;
        str[t] = cosf(ph); str[MCONST + t] = sinf(ph);
    }
    {
        double s = 0.0;
        for (int i = t; i < NBP; i += 256) s += partials[i];
        #pragma unroll
        for (int off = 32; off > 0; off >>= 1) s += __shfl_down(s, off);
        if ((t & 63) == 0) wred[t >> 6] = s;
    }
    __syncthreads();
    if (t == 0) sinv = 70.0f / (float)sqrt((wred[0] + wred[1]) + (wred[2] + wred[3]));
    if (t == 1) {
        int iv = *snr_p;
        float sv = (iv >= -1000 && iv <= 1000) ? (float)iv
                                               : *reinterpret_cast<const float*>(snr_p);
        float snr_lin = powf(10.0f, 0.1f * sv);
        ninv = 1.0f / sqrtf((float)(8.0 / 7.0) * snr_lin);
    }
    __syncthreads();
    #pragma unroll
    for (int c = 0; c < 2; ++c) {
        int lrow = c * 256 + t, row = base_row + lrow;
        if (row >= B) continue;
        const float4* ep = reinterpret_cast<const float4*>(enc + (size_t)row * 8);
        float4 e0 = ep[0], e1 = ep[1];
        float ev[7] = {e0.x, e0.y, e0.z, e0.w, e1.x, e1.y, e1.z};
        float sr[CD], si[CD], sgn[CD];
        #pragma unroll
        for (int o = 0; o < CD; ++o) {
            float es = ev[o] * sinv;
            float rv = rintf(es);
            int xi = (int)rv;
            sgn[o] = (xi < 0) ? -1.0f : 1.0f;
            int idx = (xi < 0 ? -xi : xi) & (MCONST - 1);
            sr[o] = str[idx]; si[o] = str[MCONST + idx];
        }
        float res[CD];
        #pragma unroll
        for (int k = 0; k < CD; ++k) {
            float yr = 0.f, yi = 0.f;
            #pragma unroll
            for (int cc = 0; cc < CD; ++cc) {
                float g = sG[k * CD + cc];
                yr = fmaf(g, sr[cc], yr); yi = fmaf(g, si[cc], yi);
            }
            float ang = atan2f(yi, yr);
            float q = ang * (float)(128.0 / (2.0 * 3.14159265358979323846));
            float r = rintf(q);
            float m = (r < 0.0f) ? r + 128.0f : r;
            res[k] = fmaf(noise[(size_t)row * CD + k], ninv, m * sgn[k]);
        }
        float dd[16];
        #pragma unroll
        for (int i = 0; i < 16; ++i) {
            float acc = bd1[i];
            #pragma unroll
            for (int cc = 0; cc < CD; ++cc) acc = fmaf(Wd1[i*CD+cc], res[cc], acc);
            dd[i] = (acc >= 0.f) ? acc : 0.01f * acc;
        }
        float4* op = reinterpret_cast<float4*>(out + (size_t)row * IN_DIM);
        #pragma unroll
        for (int q4 = 0; q4 < 4; ++q4) {
            float o0[4];
            #pragma unroll
            for (int u = 0; u < 4; ++u) {
                int i = q4 * 4 + u;
                float acc = bd2[i];
                #pragma unroll
                for (int j = 0; j < 16; ++j) acc = fmaf(Wd2[i*16+j], dd[j], acc);
                o0[u] = acc;
            }
            op[q4] = make_float4(o0[0], o0[1], o0[2], o0[3]);
        }
    }
}

// ---------------------------------------------------------------------------
extern "C" void kernel_launch(void* const* d_in, const int* in_sizes, int n_in,
                              void* d_out, int out_size, void* d_ws, size_t ws_size,
                              hipStream_t stream)
{
    const float* x    = (const float*)d_in[0];
    const float* We1  = (const float*)d_in[1];
    const float* be1  = (const float*)d_in[2];
    const float* We2  = (const float*)d_in[3];
    const float* be2  = (const float*)d_in[4];
    const float* Wd1  = (const float*)d_in[5];
    const float* bd1  = (const float*)d_in[6];
    const float* Wd2  = (const float*)d_in[7];
    const float* bd2  = (const float*)d_in[8];
    const float* h_lp = (const float*)d_in[9];
    const float* h_ps = (const float*)d_in[10];
    const float* noise= (const float*)d_in[11];
    const int*   snr  = (const int*)d_in[12];
    float* out = (float*)d_out;

    int B  = in_sizes[0] / IN_DIM;
    int NB = (B + 255) / 256;

    char* ws = (char*)d_ws;

    if (NB <= 512) {
        // zero barrier region [8192, 14592)
        hipMemsetAsync(ws + 8192, 0, 6400, stream);
        k_fused<<<NB, 256, 0, stream>>>(x, We1, be1, We2, be2, Wd1, bd1,
                                        Wd2, bd2, h_lp, h_ps, noise, snr,
                                        ws, out, B, NB);
    } else {
        double* partials = (double*)(ws + 0);
        float*  Gd       = (float*) (ws + 4096);
        float*  enc      = (float*) (ws + 16384);
        int NB2 = (B + 511) / 512;
        k1_enc<<<NB, 256, 0, stream>>>(x, We1, be1, We2, be2, h_lp, h_ps,
                                       enc, partials, Gd, B);
        k2_main<<<NB2, 256, 0, stream>>>(enc, Wd1, bd1, Wd2, bd2, noise, snr,
                                         partials, Gd, out, B, NB);
    }
}

// Round 18
// 27.382 us; speedup vs baseline: 1.1335x; 1.1335x over previous
//
#include <hip/hip_runtime.h>
#include <math.h>

#define IN_DIM   16
#define CD       7
#define SAMPS    20
#define KFILT    101
#define SIGLEN   140      // CD * SAMPS
#define MCONST   128      // 2^CD

// ws layout (bytes):
//   [0     .. 4096)  : double partials[512]          (atomic relaxed agent)
//   [4096  .. 6144)  : float  GR[8][64]  G replicas  (atomic relaxed agent)
//   [8192  .. 14592) : barrier region — memset each launch:
//       L0[g]  u32 @  8192 + g*256  (g<8)   group arrival counters
//       GS[g]  f64 @ 10240 + g*256  (g<8)   group sums
//       ROOT   u32 @ 12288                  root counter
//       FLAG[r]u32 @ 12544 + r*256  (r<8)   release flags; value = norm bits
//   [16384 .. +4.2MB): float enc[B][8]               (fallback path only)

__device__ __forceinline__ unsigned ld_u32(const void* p) {
    return __hip_atomic_load((const unsigned*)p, __ATOMIC_RELAXED,
                             __HIP_MEMORY_SCOPE_AGENT);
}
__device__ __forceinline__ void st_u32(void* p, unsigned v) {
    __hip_atomic_store((unsigned*)p, v, __ATOMIC_RELAXED,
                       __HIP_MEMORY_SCOPE_AGENT);
}
__device__ __forceinline__ unsigned add_u32(void* p) {
    return __hip_atomic_fetch_add((unsigned*)p, 1u, __ATOMIC_RELAXED,
                                  __HIP_MEMORY_SCOPE_AGENT);
}
__device__ __forceinline__ double ld_f64(const void* p) {
    return __hip_atomic_load((const double*)p, __ATOMIC_RELAXED,
                             __HIP_MEMORY_SCOPE_AGENT);
}
__device__ __forceinline__ void st_f64(void* p, double v) {
    __hip_atomic_store((double*)p, v, __ATOMIC_RELAXED,
                       __HIP_MEMORY_SCOPE_AGENT);
}
__device__ __forceinline__ float ld_f32(const void* p) {
    return __hip_atomic_load((const float*)p, __ATOMIC_RELAXED,
                             __HIP_MEMORY_SCOPE_AGENT);
}
__device__ __forceinline__ void st_f32(void* p, float v) {
    __hip_atomic_store((float*)p, v, __ATOMIC_RELAXED,
                       __HIP_MEMORY_SCOPE_AGENT);
}

// ---------------------------------------------------------------------------
// Fused single kernel (grid = NB <= 512, 2 blocks/CU co-resident).
// LDS staging for all reused small tables (weights, trig) — r17 showed
// per-lane VMEM re-reads cost ~+4.5 cyc/access vs ds_read broadcast.
// ---------------------------------------------------------------------------
__global__ __launch_bounds__(256, 2) void k_fused(
    const float* __restrict__ x,
    const float* __restrict__ We1, const float* __restrict__ be1,
    const float* __restrict__ We2, const float* __restrict__ be2,
    const float* __restrict__ Wd1, const float* __restrict__ bd1,
    const float* __restrict__ Wd2, const float* __restrict__ bd2,
    const float* __restrict__ h_lp, const float* __restrict__ h_ps,
    const float* __restrict__ noise, const int* __restrict__ snr_p,
    char* __restrict__ ws, float* __restrict__ out, int B, int NB)
{
    int t   = threadIdx.x;
    int bid = blockIdx.x;
    int row = bid * 256 + t;

    double* partials = (double*)(ws + 0);
    float*  GR       = (float*) (ws + 4096);
    char*   L0       = ws + 8192;
    char*   GS       = ws + 10240;
    char*   ROOT     = ws + 12288;
    char*   FLAG     = ws + 12544;

    __shared__ float    sW1[256], sW2[112], sb1[16], sb2[7];
    __shared__ float    sV1[112], sV2[256], sc1[16], sc2[16];
    __shared__ float    str[2 * MCONST];
    __shared__ double   wred[4];
    __shared__ float    sG[49];
    __shared__ float    curp[240], nxtp[240];   // [50 pad | 140 | 50 pad]
    __shared__ float    hA[KFILT], hB[KFILT];   // h_ps, h_lp
    __shared__ unsigned sNormBits;
    __shared__ float    ninv;

    // ---------------- phase-1 loads (everything hoisted) ----------------
    sW1[t] = We1[t];  sV2[t] = Wd2[t];
    if (t < 112) { sW2[t] = We2[t]; sV1[t] = Wd1[t]; }
    if (t < 16)  { sb1[t] = be1[t]; sc1[t] = bd1[t]; sc2[t] = bd2[t]; }
    if (t < 7)   sb2[t] = be2[t];
    if (bid < CD && t < KFILT) { hA[t] = h_ps[t]; hB[t] = h_lp[t]; }
    if (t < MCONST) {
        float ph = (float)(2.0 * 3.14159265358979323846 / (double)MCONST) * (float)t;
        str[t]          = cosf(ph);
        str[MCONST + t] = sinf(ph);
    }
    __syncthreads();

    // ---------------- encoder (e stays in registers) ----------------
    float e[CD];
    double ss = 0.0;
    if (row < B) {
        const float4* xp = reinterpret_cast<const float4*>(x + (size_t)row * IN_DIM);
        float4 v0 = xp[0], v1 = xp[1], v2 = xp[2], v3 = xp[3];
        float xr[16] = {v0.x,v0.y,v0.z,v0.w, v1.x,v1.y,v1.z,v1.w,
                        v2.x,v2.y,v2.z,v2.w, v3.x,v3.y,v3.z,v3.w};
        float h[16];
        #pragma unroll
        for (int i = 0; i < 16; ++i) {
            float acc = sb1[i];
            #pragma unroll
            for (int j = 0; j < 16; ++j) acc = fmaf(sW1[i*16+j], xr[j], acc);
            h[i] = (acc >= 0.f) ? acc : 0.01f * acc;
        }
        #pragma unroll
        for (int o = 0; o < CD; ++o) {
            float acc = sb2[o];
            #pragma unroll
            for (int i = 0; i < 16; ++i) acc = fmaf(sW2[o*16+i], h[i], acc);
            e[o] = acc;
            ss += (double)acc * (double)acc;
        }
    }
    // wave shfl reduce (f64), one barrier; store partial (wave-0 global store)
    double v = ss;
    #pragma unroll
    for (int off = 32; off > 0; off >>= 1) v += __shfl_down(v, off);
    if ((t & 63) == 0) wred[t >> 6] = v;
    __syncthreads();
    if (t == 0) st_f64(&partials[bid], (wred[0] + wred[1]) + (wred[2] + wred[3]));

    // ---------------- G column (blocks 0..6), f32, -> 8 replicas ----------
    if (bid < CD) {
        if (t < 240) { curp[t] = 0.0f; nxtp[t] = 0.0f; }
        __syncthreads();
        if (t < SIGLEN) {
            int m = t + 50 - SAMPS * bid;    // conv(delta, h_ps) = shifted h_ps
            curp[t + 50] = (m >= 0 && m < KFILT) ? hA[m] : 0.0f;
        }
        __syncthreads();
        for (int f = 0; f < 2; ++f) {
            const float* h = (f == 0) ? hB : hA;   // lowpass, then pulseshape
            if (t < SIGLEN) {
                float a0 = 0.f, a1 = 0.f;
                for (int m = 0; m <= 50; ++m)    a0 = fmaf(h[m], curp[t + 100 - m], a0);
                for (int m = 51; m < KFILT; ++m) a1 = fmaf(h[m], curp[t + 100 - m], a1);
                nxtp[t + 50] = a0 + a1;
            }
            __syncthreads();
            if (t < SIGLEN) curp[t + 50] = nxtp[t + 50];
            __syncthreads();
        }
        if (t < CD) {   // wave-0 lanes 0..6: store into all 8 replicas
            float gv = (float)SAMPS * curp[t * SAMPS + 50];
            #pragma unroll
            for (int r = 0; r < 8; ++r)
                st_f32(&GR[r * 64 + t * CD + bid], gv);
        }
    }

    // ---------------- pre-barrier hoisted work ----------------
    // noise prefetched straight into registers; latency hides under barrier
    float nz[CD];
    if (row < B) {
        const float* np0 = noise + (size_t)row * CD;
        #pragma unroll
        for (int k = 0; k < CD; ++k) nz[k] = np0[k];
    } else {
        #pragma unroll
        for (int k = 0; k < CD; ++k) nz[k] = 0.f;
    }
    if (t == 1) {
        int iv = *snr_p;
        float sv = (iv >= -1000 && iv <= 1000) ? (float)iv
                                               : *reinterpret_cast<const float*>(snr_p);
        float snr_lin = powf(10.0f, 0.1f * sv);
        ninv = 1.0f / sqrtf((float)(8.0 / 7.0) * snr_lin);  // 1/sqrt(2*rate*snr)
    }

    // ---------------- barrier: tree arrival, wave-parallel reduce,
    //                  flag carries norm bits ----------------
    __syncthreads();          // all waves done; all global stores were wave-0's
    if (t < 64) {
        asm volatile("s_waitcnt vmcnt(0)" ::: "memory");  // wave-0 stores at LLC
        int g       = bid >> 6;
        int gbase   = g << 6;
        int gsize   = (NB - gbase < 64) ? (NB - gbase) : 64;
        int ngroups = (NB + 63) >> 6;

        unsigned aret = 0;
        if (t == 0) aret = add_u32(L0 + (size_t)g * 256);
        aret = __shfl(aret, 0);
        if ((int)aret == gsize - 1) {
            // group-last: WAVE-PARALLEL reduce of this group's partials
            double p = (t < gsize) ? ld_f64(&partials[gbase + t]) : 0.0;
            #pragma unroll
            for (int off = 32; off > 0; off >>= 1) p += __shfl_down(p, off);
            unsigned rret = 0;
            if (t == 0) {
                st_f64(GS + (size_t)g * 256, p);
                asm volatile("s_waitcnt vmcnt(0)" ::: "memory");
                rret = add_u32(ROOT);
            }
            rret = __shfl(rret, 0);
            if ((int)rret == ngroups - 1) {
                // root-last: wave-parallel reduce of group sums -> norm
                double gsv = (t < ngroups) ? ld_f64(GS + (size_t)t * 256) : 0.0;
                #pragma unroll
                for (int off = 32; off > 0; off >>= 1) gsv += __shfl_down(gsv, off);
                unsigned bits = 0;
                if (t == 0) bits = __float_as_uint((float)sqrt(gsv));
                bits = __shfl(bits, 0);
                if (t < 8) st_u32(FLAG + (size_t)t * 256, bits);
            }
        }
        // release: poll own flag replica; its VALUE is the norm
        if (t == 0) {
            unsigned b2;
            while ((b2 = ld_u32(FLAG + (size_t)(bid & 7) * 256)) == 0u)
                __builtin_amdgcn_s_sleep(2);
            sNormBits = b2;
        }
        // after release, G replicas are globally visible: fetch ours
        if (t < 49) sG[t] = ld_f32(&GR[(size_t)(bid & 7) * 64 + t]);
    }
    __syncthreads();
    float sinv = 70.0f / __uint_as_float(sNormBits);

    // ---------------- phase 2 ----------------
    if (row >= B) return;

    float sr[CD], si[CD], sgn[CD], fidx[CD];
    #pragma unroll
    for (int o = 0; o < CD; ++o) {
        float es = e[o] * sinv;                  // enc * (70/||enc||)
        float rv = rintf(es);                    // jnp.round = half-to-even
        int xi = (int)rv;
        sgn[o] = (xi < 0) ? -1.0f : 1.0f;
        int idx = (xi < 0 ? -xi : xi) & (MCONST - 1);   // mod(|xi|, 128)
        fidx[o] = (float)idx;
        sr[o] = str[idx];
        si[o] = str[MCONST + idx];
    }

    const float QSC = 20.37183271576260f;        // 128 / (2*pi)
    float res[CD];
    #pragma unroll
    for (int k = 0; k < CD; ++k) {
        float yr = 0.f, yi = 0.f;
        #pragma unroll
        for (int cc = 0; cc < CD; ++cc) {
            float g = sG[k * CD + cc];
            yr = fmaf(g, sr[cc], yr);
            yi = fmaf(g, si[cc], yi);
        }
        // rotate by conj(transmitted symbol k): ang = phi_idx + atan2(b, a)
        float c = sr[k], s = si[k];
        float a = fmaf(yr, c, yi * s);           // yr*c + yi*s
        float b = fmaf(yi, c, -(yr * s));        // yi*c - yr*s
        float q;
        if (fabsf(b) < 0.25f * a) {              // small-angle & a>0: poly atan
            float u  = b / a;
            float u2 = u * u;
            float w  = fmaf(u2, -0.142857143f, 0.2f);     // -1/7, +1/5
            w        = fmaf(u2, w, -0.333333333f);        // -1/3
            w        = fmaf(u2, w, 1.0f);
            q = fmaf(u * w, QSC, fidx[k]);
        } else {                                 // rare: exact fallback
            q = fmaf(atan2f(b, a), QSC, fidx[k]);
        }
        float r = rintf(q);                      // q in [-64, 191]
        if (r < 0.0f) r += 128.0f;
        else if (r >= 128.0f) r -= 128.0f;       // jnp.mod semantics
        res[k] = fmaf(nz[k], ninv, r * sgn[k]);
    }

    float dd[16];
    #pragma unroll
    for (int i = 0; i < 16; ++i) {
        float acc = sc1[i];
        #pragma unroll
        for (int cc = 0; cc < CD; ++cc) acc = fmaf(sV1[i*CD+cc], res[cc], acc);
        dd[i] = (acc >= 0.f) ? acc : 0.01f * acc;
    }
    float4* op = reinterpret_cast<float4*>(out + (size_t)row * IN_DIM);
    #pragma unroll
    for (int q4 = 0; q4 < 4; ++q4) {
        float o0[4];
        #pragma unroll
        for (int u = 0; u < 4; ++u) {
            int i = q4 * 4 + u;
            float acc = sc2[i];
            #pragma unroll
            for (int j = 0; j < 16; ++j) acc = fmaf(sV2[i*16+j], dd[j], acc);
            o0[u] = acc;
        }
        op[q4] = make_float4(o0[0], o0[1], o0[2], o0[3]);
    }
}

// ---------------------------------------------------------------------------
// Fallback 2-kernel path (r14, proven) for NB > 512
// ---------------------------------------------------------------------------
__global__ __launch_bounds__(256) void k1_enc(
    const float* __restrict__ x,
    const float* __restrict__ We1, const float* __restrict__ be1,
    const float* __restrict__ We2, const float* __restrict__ be2,
    const float* __restrict__ h_lp, const float* __restrict__ h_ps,
    float* __restrict__ enc, double* __restrict__ partials,
    float* __restrict__ Gd, int B)
{
    int t = threadIdx.x, bid = blockIdx.x, row = bid * 256 + t;
    __shared__ float  sW1[256], sW2[112], sb1[16], sb2[7];
    __shared__ double wred[4];
    __shared__ float  curp[240], nxtp[240];
    __shared__ float  hA[KFILT], hB[KFILT];
    sW1[t] = We1[t];
    if (t < 112) sW2[t] = We2[t];
    if (t < 16)  sb1[t] = be1[t];
    if (t < 7)   sb2[t] = be2[t];
    if (bid < CD && t < KFILT) { hA[t] = h_ps[t]; hB[t] = h_lp[t]; }
    __syncthreads();
    double ss = 0.0;
    if (row < B) {
        const float4* xp = reinterpret_cast<const float4*>(x + (size_t)row * IN_DIM);
        float4 v0 = xp[0], v1 = xp[1], v2 = xp[2], v3 = xp[3];
        float xr[16] = {v0.x,v0.y,v0.z,v0.w, v1.x,v1.y,v1.z,v1.w,
                        v2.x,v2.y,v2.z,v2.w, v3.x,v3.y,v3.z,v3.w};
        float h[16];
        #pragma unroll
        for (int i = 0; i < 16; ++i) {
            float acc = sb1[i];
            #pragma unroll
            for (int j = 0; j < 16; ++j) acc = fmaf(sW1[i*16+j], xr[j], acc);
            h[i] = (acc >= 0.f) ? acc : 0.01f * acc;
        }
        float e[8];
        #pragma unroll
        for (int o = 0; o < CD; ++o) {
            float acc = sb2[o];
            #pragma unroll
            for (int i = 0; i < 16; ++i) acc = fmaf(sW2[o*16+i], h[i], acc);
            e[o] = acc; ss += (double)acc * (double)acc;
        }
        e[7] = 0.f;
        float4* ep = reinterpret_cast<float4*>(enc + (size_t)row * 8);
        ep[0] = make_float4(e[0], e[1], e[2], e[3]);
        ep[1] = make_float4(e[4], e[5], e[6], e[7]);
    }
    double v = ss;
    #pragma unroll
    for (int off = 32; off > 0; off >>= 1) v += __shfl_down(v, off);
    if ((t & 63) == 0) wred[t >> 6] = v;
    __syncthreads();
    if (t == 0) partials[bid] = (wred[0] + wred[1]) + (wred[2] + wred[3]);
    if (bid < CD) {
        if (t < 240) { curp[t] = 0.0f; nxtp[t] = 0.0f; }
        __syncthreads();
        if (t < SIGLEN) {
            int m = t + 50 - SAMPS * bid;
            curp[t + 50] = (m >= 0 && m < KFILT) ? hA[m] : 0.0f;
        }
        __syncthreads();
        for (int f = 0; f < 2; ++f) {
            const float* h = (f == 0) ? hB : hA;
            if (t < SIGLEN) {
                float a0 = 0.f, a1 = 0.f;
                for (int m = 0; m <= 50; ++m)    a0 = fmaf(h[m], curp[t + 100 - m], a0);
                for (int m = 51; m < KFILT; ++m) a1 = fmaf(h[m], curp[t + 100 - m], a1);
                nxtp[t + 50] = a0 + a1;
            }
            __syncthreads();
            if (t < SIGLEN) curp[t + 50] = nxtp[t + 50];
            __syncthreads();
        }
        if (t < CD) Gd[t * CD + bid] = (float)SAMPS * curp[t * SAMPS + 50];
    }
}

__global__ __launch_bounds__(256) void k2_main(
    const float* __restrict__ enc,
    const float* __restrict__ Wd1, const float* __restrict__ bd1,
    const float* __restrict__ Wd2, const float* __restrict__ bd2,
    const float* __restrict__ noise, const int* __restrict__ snr_p,
    const double* __restrict__ partials, const float* __restrict__ Gd,
    float* __restrict__ out, int B, int NBP)
{
    int t = threadIdx.x, bid = blockIdx.x, base_row = bid * 512;
    __shared__ float  sV1[112], sc1[16], sV2[256], sc2[16];
    __shared__ float  str[2 * MCONST];
    __shared__ float  sG[49];
    __shared__ double wred[4];
    __shared__ float  snz[512 * CD];
    __shared__ float  sinv, ninv;
    sV2[t] = Wd2[t];
    if (t < 112) sV1[t] = Wd1[t];
    if (t < 16)  { sc1[t] = bd1[t]; sc2[t] = bd2[t]; }
    if (t < 49)  sG[t] = Gd[t];
    if (t < MCONST) {
        float ph = (float)(2.0 * 3.14159265358979323846 / (double)MCONST) * (float)t;
        str[t] = cosf(ph); str[MCONST + t] = sinf(ph);
    }
    {
        size_t nb = (size_t)base_row * CD, lim = (size_t)B * CD;
        for (int i = t; i < 512 * CD; i += 256)
            if (nb + i < lim) snz[i] = noise[nb + i];
    }
    {
        double s = 0.0;
        for (int i = t; i < NBP; i += 256) s += partials[i];
        #pragma unroll
        for (int off = 32; off > 0; off >>= 1) s += __shfl_down(s, off);
        if ((t & 63) == 0) wred[t >> 6] = s;
    }
    __syncthreads();
    if (t == 0) sinv = 70.0f / (float)sqrt((wred[0] + wred[1]) + (wred[2] + wred[3]));
    if (t == 1) {
        int iv = *snr_p;
        float sv = (iv >= -1000 && iv <= 1000) ? (float)iv
                                               : *reinterpret_cast<const float*>(snr_p);
        float snr_lin = powf(10.0f, 0.1f * sv);
        ninv = 1.0f / sqrtf((float)(8.0 / 7.0) * snr_lin);
    }
    __syncthreads();
    #pragma unroll
    for (int c = 0; c < 2; ++c) {
        int lrow = c * 256 + t, row = base_row + lrow;
        if (row >= B) continue;
        const float4* ep = reinterpret_cast<const float4*>(enc + (size_t)row * 8);
        float4 e0 = ep[0], e1 = ep[1];
        float ev[7] = {e0.x, e0.y, e0.z, e0.w, e1.x, e1.y, e1.z};
        float sr[CD], si[CD], sgn[CD];
        #pragma unroll
        for (int o = 0; o < CD; ++o) {
            float es = ev[o] * sinv;
            float rv = rintf(es);
            int xi = (int)rv;
            sgn[o] = (xi < 0) ? -1.0f : 1.0f;
            int idx = (xi < 0 ? -xi : xi) & (MCONST - 1);
            sr[o] = str[idx]; si[o] = str[MCONST + idx];
        }
        float res[CD];
        #pragma unroll
        for (int k = 0; k < CD; ++k) {
            float yr = 0.f, yi = 0.f;
            #pragma unroll
            for (int cc = 0; cc < CD; ++cc) {
                float g = sG[k * CD + cc];
                yr = fmaf(g, sr[cc], yr); yi = fmaf(g, si[cc], yi);
            }
            float ang = atan2f(yi, yr);
            float q = ang * (float)(128.0 / (2.0 * 3.14159265358979323846));
            float r = rintf(q);
            float m = (r < 0.0f) ? r + 128.0f : r;
            res[k] = fmaf(snz[lrow * CD + k], ninv, m * sgn[k]);
        }
        float dd[16];
        #pragma unroll
        for (int i = 0; i < 16; ++i) {
            float acc = sc1[i];
            #pragma unroll
            for (int cc = 0; cc < CD; ++cc) acc = fmaf(sV1[i*CD+cc], res[cc], acc);
            dd[i] = (acc >= 0.f) ? acc : 0.01f * acc;
        }
        float4* op = reinterpret_cast<float4*>(out + (size_t)row * IN_DIM);
        #pragma unroll
        for (int q4 = 0; q4 < 4; ++q4) {
            float o0[4];
            #pragma unroll
            for (int u = 0; u < 4; ++u) {
                int i = q4 * 4 + u;
                float acc = sc2[i];
                #pragma unroll
                for (int j = 0; j < 16; ++j) acc = fmaf(sV2[i*16+j], dd[j], acc);
                o0[u] = acc;
            }
            op[q4] = make_float4(o0[0], o0[1], o0[2], o0[3]);
        }
    }
}

// ---------------------------------------------------------------------------
extern "C" void kernel_launch(void* const* d_in, const int* in_sizes, int n_in,
                              void* d_out, int out_size, void* d_ws, size_t ws_size,
                              hipStream_t stream)
{
    const float* x    = (const float*)d_in[0];
    const float* We1  = (const float*)d_in[1];
    const float* be1  = (const float*)d_in[2];
    const float* We2  = (const float*)d_in[3];
    const float* be2  = (const float*)d_in[4];
    const float* Wd1  = (const float*)d_in[5];
    const float* bd1  = (const float*)d_in[6];
    const float* Wd2  = (const float*)d_in[7];
    const float* bd2  = (const float*)d_in[8];
    const float* h_lp = (const float*)d_in[9];
    const float* h_ps = (const float*)d_in[10];
    const float* noise= (const float*)d_in[11];
    const int*   snr  = (const int*)d_in[12];
    float* out = (float*)d_out;

    int B  = in_sizes[0] / IN_DIM;
    int NB = (B + 255) / 256;

    char* ws = (char*)d_ws;

    if (NB <= 512) {
        // zero barrier region [8192, 14592)
        hipMemsetAsync(ws + 8192, 0, 6400, stream);
        k_fused<<<NB, 256, 0, stream>>>(x, We1, be1, We2, be2, Wd1, bd1,
                                        Wd2, bd2, h_lp, h_ps, noise, snr,
                                        ws, out, B, NB);
    } else {
        double* partials = (double*)(ws + 0);
        float*  Gd       = (float*) (ws + 4096);
        float*  enc      = (float*) (ws + 16384);
        int NB2 = (B + 511) / 512;
        k1_enc<<<NB, 256, 0, stream>>>(x, We1, be1, We2, be2, h_lp, h_ps,
                                       enc, partials, Gd, B);
        k2_main<<<NB2, 256, 0, stream>>>(enc, Wd1, bd1, Wd2, bd2, noise, snr,
                                         partials, Gd, out, B, NB);
    }
}

// Round 19
// 26.999 us; speedup vs baseline: 1.1496x; 1.0142x over previous
//
#include <hip/hip_runtime.h>
#include <math.h>

#define IN_DIM   16
#define CD       7
#define SAMPS    20
#define KFILT    101
#define SIGLEN   140      // CD * SAMPS
#define MCONST   128      // 2^CD

// ws layout (bytes):
//   [0     .. 4096)  : double partials[512]          (atomic relaxed agent)
//   [4096  .. 6144)  : float  GR[8][64]  G replicas  (atomic relaxed agent)
//   [8192  .. 14592) : barrier region — memset each launch:
//       L0[g]  u32 @  8192 + g*256  (g<8)   group arrival counters
//       GS[g]  f64 @ 10240 + g*256  (g<8)   group sums
//       ROOT   u32 @ 12288                  root counter
//       FLAG[r]u32 @ 12544 + r*256  (r<8)   release flags; value = norm bits
//   [16384 .. +4.2MB): float enc[B][8]               (fallback path only)

__device__ __forceinline__ unsigned ld_u32(const void* p) {
    return __hip_atomic_load((const unsigned*)p, __ATOMIC_RELAXED,
                             __HIP_MEMORY_SCOPE_AGENT);
}
__device__ __forceinline__ void st_u32(void* p, unsigned v) {
    __hip_atomic_store((unsigned*)p, v, __ATOMIC_RELAXED,
                       __HIP_MEMORY_SCOPE_AGENT);
}
__device__ __forceinline__ unsigned add_u32(void* p) {
    return __hip_atomic_fetch_add((unsigned*)p, 1u, __ATOMIC_RELAXED,
                                  __HIP_MEMORY_SCOPE_AGENT);
}
__device__ __forceinline__ double ld_f64(const void* p) {
    return __hip_atomic_load((const double*)p, __ATOMIC_RELAXED,
                             __HIP_MEMORY_SCOPE_AGENT);
}
__device__ __forceinline__ void st_f64(void* p, double v) {
    __hip_atomic_store((double*)p, v, __ATOMIC_RELAXED,
                       __HIP_MEMORY_SCOPE_AGENT);
}
__device__ __forceinline__ float ld_f32(const void* p) {
    return __hip_atomic_load((const float*)p, __ATOMIC_RELAXED,
                             __HIP_MEMORY_SCOPE_AGENT);
}
__device__ __forceinline__ void st_f32(void* p, float v) {
    __hip_atomic_store((float*)p, v, __ATOMIC_RELAXED,
                       __HIP_MEMORY_SCOPE_AGENT);
}

// ---------------------------------------------------------------------------
// Fused single kernel (grid = NB <= 512, 2 blocks/CU co-resident).
// Weight matrices with 16-wide rows staged as float4 LDS arrays so the
// matvecs issue ds_read_b128 (4 values/instr) instead of scalar ds_read_b32.
// FMA order within each row unchanged -> bit-identical results.
// ---------------------------------------------------------------------------
__global__ __launch_bounds__(256, 2) void k_fused(
    const float* __restrict__ x,
    const float* __restrict__ We1, const float* __restrict__ be1,
    const float* __restrict__ We2, const float* __restrict__ be2,
    const float* __restrict__ Wd1, const float* __restrict__ bd1,
    const float* __restrict__ Wd2, const float* __restrict__ bd2,
    const float* __restrict__ h_lp, const float* __restrict__ h_ps,
    const float* __restrict__ noise, const int* __restrict__ snr_p,
    char* __restrict__ ws, float* __restrict__ out, int B, int NB)
{
    int t   = threadIdx.x;
    int bid = blockIdx.x;
    int row = bid * 256 + t;

    double* partials = (double*)(ws + 0);
    float*  GR       = (float*) (ws + 4096);
    char*   L0       = ws + 8192;
    char*   GS       = ws + 10240;
    char*   ROOT     = ws + 12288;
    char*   FLAG     = ws + 12544;

    __shared__ float4   sW1v[64];               // We1: 16x16 as 64 float4
    __shared__ float4   sW2v[28];               // We2: 7x16  as 28 float4
    __shared__ float4   sV2v[64];               // Wd2: 16x16 as 64 float4
    __shared__ float    sV1[112];               // Wd1: 16x7 (rows misaligned)
    __shared__ float    sb1[16], sb2[7], sc1[16], sc2[16];
    __shared__ float    str[2 * MCONST];
    __shared__ double   wred[4];
    __shared__ float    sG[49];
    __shared__ float    curp[240], nxtp[240];   // [50 pad | 140 | 50 pad]
    __shared__ float    hA[KFILT], hB[KFILT];   // h_ps, h_lp
    __shared__ unsigned sNormBits;
    __shared__ float    ninv;

    // ---------------- phase-1 loads (everything hoisted) ----------------
    if (t < 64) {
        sW1v[t] = reinterpret_cast<const float4*>(We1)[t];
        sV2v[t] = reinterpret_cast<const float4*>(Wd2)[t];
    }
    if (t < 28)  sW2v[t] = reinterpret_cast<const float4*>(We2)[t];
    if (t < 112) sV1[t] = Wd1[t];
    if (t < 16)  { sb1[t] = be1[t]; sc1[t] = bd1[t]; sc2[t] = bd2[t]; }
    if (t < 7)   sb2[t] = be2[t];
    if (bid < CD && t < KFILT) { hA[t] = h_ps[t]; hB[t] = h_lp[t]; }
    if (t < MCONST) {
        float ph = (float)(2.0 * 3.14159265358979323846 / (double)MCONST) * (float)t;
        str[t]          = cosf(ph);
        str[MCONST + t] = sinf(ph);
    }
    __syncthreads();

    // ---------------- encoder (e stays in registers) ----------------
    float e[CD];
    double ss = 0.0;
    if (row < B) {
        const float4* xp = reinterpret_cast<const float4*>(x + (size_t)row * IN_DIM);
        float4 v0 = xp[0], v1 = xp[1], v2 = xp[2], v3 = xp[3];
        float h[16];
        #pragma unroll
        for (int i = 0; i < 16; ++i) {
            float4 w0 = sW1v[i*4+0], w1 = sW1v[i*4+1],
                   w2 = sW1v[i*4+2], w3 = sW1v[i*4+3];
            float acc = sb1[i];
            acc = fmaf(w0.x, v0.x, acc); acc = fmaf(w0.y, v0.y, acc);
            acc = fmaf(w0.z, v0.z, acc); acc = fmaf(w0.w, v0.w, acc);
            acc = fmaf(w1.x, v1.x, acc); acc = fmaf(w1.y, v1.y, acc);
            acc = fmaf(w1.z, v1.z, acc); acc = fmaf(w1.w, v1.w, acc);
            acc = fmaf(w2.x, v2.x, acc); acc = fmaf(w2.y, v2.y, acc);
            acc = fmaf(w2.z, v2.z, acc); acc = fmaf(w2.w, v2.w, acc);
            acc = fmaf(w3.x, v3.x, acc); acc = fmaf(w3.y, v3.y, acc);
            acc = fmaf(w3.z, v3.z, acc); acc = fmaf(w3.w, v3.w, acc);
            h[i] = (acc >= 0.f) ? acc : 0.01f * acc;
        }
        #pragma unroll
        for (int o = 0; o < CD; ++o) {
            float4 w0 = sW2v[o*4+0], w1 = sW2v[o*4+1],
                   w2 = sW2v[o*4+2], w3 = sW2v[o*4+3];
            float acc = sb2[o];
            acc = fmaf(w0.x, h[0],  acc); acc = fmaf(w0.y, h[1],  acc);
            acc = fmaf(w0.z, h[2],  acc); acc = fmaf(w0.w, h[3],  acc);
            acc = fmaf(w1.x, h[4],  acc); acc = fmaf(w1.y, h[5],  acc);
            acc = fmaf(w1.z, h[6],  acc); acc = fmaf(w1.w, h[7],  acc);
            acc = fmaf(w2.x, h[8],  acc); acc = fmaf(w2.y, h[9],  acc);
            acc = fmaf(w2.z, h[10], acc); acc = fmaf(w2.w, h[11], acc);
            acc = fmaf(w3.x, h[12], acc); acc = fmaf(w3.y, h[13], acc);
            acc = fmaf(w3.z, h[14], acc); acc = fmaf(w3.w, h[15], acc);
            e[o] = acc;
            ss += (double)acc * (double)acc;
        }
    }
    // wave shfl reduce (f64), one barrier; store partial (wave-0 global store)
    double v = ss;
    #pragma unroll
    for (int off = 32; off > 0; off >>= 1) v += __shfl_down(v, off);
    if ((t & 63) == 0) wred[t >> 6] = v;
    __syncthreads();
    if (t == 0) st_f64(&partials[bid], (wred[0] + wred[1]) + (wred[2] + wred[3]));

    // ---------------- G column (blocks 0..6), f32, -> 8 replicas ----------
    if (bid < CD) {
        if (t < 240) { curp[t] = 0.0f; nxtp[t] = 0.0f; }
        __syncthreads();
        if (t < SIGLEN) {
            int m = t + 50 - SAMPS * bid;    // conv(delta, h_ps) = shifted h_ps
            curp[t + 50] = (m >= 0 && m < KFILT) ? hA[m] : 0.0f;
        }
        __syncthreads();
        for (int f = 0; f < 2; ++f) {
            const float* h = (f == 0) ? hB : hA;   // lowpass, then pulseshape
            if (t < SIGLEN) {
                float a0 = 0.f, a1 = 0.f;
                for (int m = 0; m <= 50; ++m)    a0 = fmaf(h[m], curp[t + 100 - m], a0);
                for (int m = 51; m < KFILT; ++m) a1 = fmaf(h[m], curp[t + 100 - m], a1);
                nxtp[t + 50] = a0 + a1;
            }
            __syncthreads();
            if (t < SIGLEN) curp[t + 50] = nxtp[t + 50];
            __syncthreads();
        }
        if (t < CD) {   // wave-0 lanes 0..6: store into all 8 replicas
            float gv = (float)SAMPS * curp[t * SAMPS + 50];
            #pragma unroll
            for (int r = 0; r < 8; ++r)
                st_f32(&GR[r * 64 + t * CD + bid], gv);
        }
    }

    // ---------------- pre-barrier hoisted work ----------------
    // noise prefetched straight into registers; latency hides under barrier
    float nz[CD];
    if (row < B) {
        const float* np0 = noise + (size_t)row * CD;
        #pragma unroll
        for (int k = 0; k < CD; ++k) nz[k] = np0[k];
    } else {
        #pragma unroll
        for (int k = 0; k < CD; ++k) nz[k] = 0.f;
    }
    if (t == 1) {
        int iv = *snr_p;
        float sv = (iv >= -1000 && iv <= 1000) ? (float)iv
                                               : *reinterpret_cast<const float*>(snr_p);
        float snr_lin = powf(10.0f, 0.1f * sv);
        ninv = 1.0f / sqrtf((float)(8.0 / 7.0) * snr_lin);  // 1/sqrt(2*rate*snr)
    }

    // ---------------- barrier: tree arrival, wave-parallel reduce,
    //                  flag carries norm bits ----------------
    __syncthreads();          // all waves done; all global stores were wave-0's
    if (t < 64) {
        asm volatile("s_waitcnt vmcnt(0)" ::: "memory");  // wave-0 stores at LLC
        int g       = bid >> 6;
        int gbase   = g << 6;
        int gsize   = (NB - gbase < 64) ? (NB - gbase) : 64;
        int ngroups = (NB + 63) >> 6;

        unsigned aret = 0;
        if (t == 0) aret = add_u32(L0 + (size_t)g * 256);
        aret = __shfl(aret, 0);
        if ((int)aret == gsize - 1) {
            // group-last: WAVE-PARALLEL reduce of this group's partials
            double p = (t < gsize) ? ld_f64(&partials[gbase + t]) : 0.0;
            #pragma unroll
            for (int off = 32; off > 0; off >>= 1) p += __shfl_down(p, off);
            unsigned rret = 0;
            if (t == 0) {
                st_f64(GS + (size_t)g * 256, p);
                asm volatile("s_waitcnt vmcnt(0)" ::: "memory");
                rret = add_u32(ROOT);
            }
            rret = __shfl(rret, 0);
            if ((int)rret == ngroups - 1) {
                // root-last: wave-parallel reduce of group sums -> norm
                double gsv = (t < ngroups) ? ld_f64(GS + (size_t)t * 256) : 0.0;
                #pragma unroll
                for (int off = 32; off > 0; off >>= 1) gsv += __shfl_down(gsv, off);
                unsigned bits = 0;
                if (t == 0) bits = __float_as_uint((float)sqrt(gsv));
                bits = __shfl(bits, 0);
                if (t < 8) st_u32(FLAG + (size_t)t * 256, bits);
            }
        }
        // release: poll own flag replica; its VALUE is the norm
        if (t == 0) {
            unsigned b2;
            while ((b2 = ld_u32(FLAG + (size_t)(bid & 7) * 256)) == 0u)
                __builtin_amdgcn_s_sleep(2);
            sNormBits = b2;
        }
        // after release, G replicas are globally visible: fetch ours
        if (t < 49) sG[t] = ld_f32(&GR[(size_t)(bid & 7) * 64 + t]);
    }
    __syncthreads();
    float sinv = 70.0f / __uint_as_float(sNormBits);

    // ---------------- phase 2 ----------------
    if (row >= B) return;

    float sr[CD], si[CD], sgn[CD], fidx[CD];
    #pragma unroll
    for (int o = 0; o < CD; ++o) {
        float es = e[o] * sinv;                  // enc * (70/||enc||)
        float rv = rintf(es);                    // jnp.round = half-to-even
        int xi = (int)rv;
        sgn[o] = (xi < 0) ? -1.0f : 1.0f;
        int idx = (xi < 0 ? -xi : xi) & (MCONST - 1);   // mod(|xi|, 128)
        fidx[o] = (float)idx;
        sr[o] = str[idx];
        si[o] = str[MCONST + idx];
    }

    const float QSC = 20.37183271576260f;        // 128 / (2*pi)
    float res[CD];
    #pragma unroll
    for (int k = 0; k < CD; ++k) {
        float yr = 0.f, yi = 0.f;
        #pragma unroll
        for (int cc = 0; cc < CD; ++cc) {
            float g = sG[k * CD + cc];
            yr = fmaf(g, sr[cc], yr);
            yi = fmaf(g, si[cc], yi);
        }
        // rotate by conj(transmitted symbol k): ang = phi_idx + atan2(b, a)
        float c = sr[k], s = si[k];
        float a = fmaf(yr, c, yi * s);           // yr*c + yi*s
        float b = fmaf(yi, c, -(yr * s));        // yi*c - yr*s
        float q;
        if (fabsf(b) < 0.25f * a) {              // small-angle & a>0: poly atan
            float u  = b / a;
            float u2 = u * u;
            float w  = fmaf(u2, -0.142857143f, 0.2f);     // -1/7, +1/5
            w        = fmaf(u2, w, -0.333333333f);        // -1/3
            w        = fmaf(u2, w, 1.0f);
            q = fmaf(u * w, QSC, fidx[k]);
        } else {                                 // rare: exact fallback
            q = fmaf(atan2f(b, a), QSC, fidx[k]);
        }
        float r = rintf(q);                      // q in [-64, 191]
        if (r < 0.0f) r += 128.0f;
        else if (r >= 128.0f) r -= 128.0f;       // jnp.mod semantics
        res[k] = fmaf(nz[k], ninv, r * sgn[k]);
    }

    float dd[16];
    #pragma unroll
    for (int i = 0; i < 16; ++i) {
        float acc = sc1[i];
        #pragma unroll
        for (int cc = 0; cc < CD; ++cc) acc = fmaf(sV1[i*CD+cc], res[cc], acc);
        dd[i] = (acc >= 0.f) ? acc : 0.01f * acc;
    }
    float4* op = reinterpret_cast<float4*>(out + (size_t)row * IN_DIM);
    #pragma unroll
    for (int q4 = 0; q4 < 4; ++q4) {
        float o0[4];
        #pragma unroll
        for (int u = 0; u < 4; ++u) {
            int i = q4 * 4 + u;
            float4 w0 = sV2v[i*4+0], w1 = sV2v[i*4+1],
                   w2 = sV2v[i*4+2], w3 = sV2v[i*4+3];
            float acc = sc2[i];
            acc = fmaf(w0.x, dd[0],  acc); acc = fmaf(w0.y, dd[1],  acc);
            acc = fmaf(w0.z, dd[2],  acc); acc = fmaf(w0.w, dd[3],  acc);
            acc = fmaf(w1.x, dd[4],  acc); acc = fmaf(w1.y, dd[5],  acc);
            acc = fmaf(w1.z, dd[6],  acc); acc = fmaf(w1.w, dd[7],  acc);
            acc = fmaf(w2.x, dd[8],  acc); acc = fmaf(w2.y, dd[9],  acc);
            acc = fmaf(w2.z, dd[10], acc); acc = fmaf(w2.w, dd[11], acc);
            acc = fmaf(w3.x, dd[12], acc); acc = fmaf(w3.y, dd[13], acc);
            acc = fmaf(w3.z, dd[14], acc); acc = fmaf(w3.w, dd[15], acc);
            o0[u] = acc;
        }
        op[q4] = make_float4(o0[0], o0[1], o0[2], o0[3]);
    }
}

// ---------------------------------------------------------------------------
// Fallback 2-kernel path (r14, proven) for NB > 512
// ---------------------------------------------------------------------------
__global__ __launch_bounds__(256) void k1_enc(
    const float* __restrict__ x,
    const float* __restrict__ We1, const float* __restrict__ be1,
    const float* __restrict__ We2, const float* __restrict__ be2,
    const float* __restrict__ h_lp, const float* __restrict__ h_ps,
    float* __restrict__ enc, double* __restrict__ partials,
    float* __restrict__ Gd, int B)
{
    int t = threadIdx.x, bid = blockIdx.x, row = bid * 256 + t;
    __shared__ float  sW1[256], sW2[112], sb1[16], sb2[7];
    __shared__ double wred[4];
    __shared__ float  curp[240], nxtp[240];
    __shared__ float  hA[KFILT], hB[KFILT];
    sW1[t] = We1[t];
    if (t < 112) sW2[t] = We2[t];
    if (t < 16)  sb1[t] = be1[t];
    if (t < 7)   sb2[t] = be2[t];
    if (bid < CD && t < KFILT) { hA[t] = h_ps[t]; hB[t] = h_lp[t]; }
    __syncthreads();
    double ss = 0.0;
    if (row < B) {
        const float4* xp = reinterpret_cast<const float4*>(x + (size_t)row * IN_DIM);
        float4 v0 = xp[0], v1 = xp[1], v2 = xp[2], v3 = xp[3];
        float xr[16] = {v0.x,v0.y,v0.z,v0.w, v1.x,v1.y,v1.z,v1.w,
                        v2.x,v2.y,v2.z,v2.w, v3.x,v3.y,v3.z,v3.w};
        float h[16];
        #pragma unroll
        for (int i = 0; i < 16; ++i) {
            float acc = sb1[i];
            #pragma unroll
            for (int j = 0; j < 16; ++j) acc = fmaf(sW1[i*16+j], xr[j], acc);
            h[i] = (acc >= 0.f) ? acc : 0.01f * acc;
        }
        float e[8];
        #pragma unroll
        for (int o = 0; o < CD; ++o) {
            float acc = sb2[o];
            #pragma unroll
            for (int i = 0; i < 16; ++i) acc = fmaf(sW2[o*16+i], h[i], acc);
            e[o] = acc; ss += (double)acc * (double)acc;
        }
        e[7] = 0.f;
        float4* ep = reinterpret_cast<float4*>(enc + (size_t)row * 8);
        ep[0] = make_float4(e[0], e[1], e[2], e[3]);
        ep[1] = make_float4(e[4], e[5], e[6], e[7]);
    }
    double v = ss;
    #pragma unroll
    for (int off = 32; off > 0; off >>= 1) v += __shfl_down(v, off);
    if ((t & 63) == 0) wred[t >> 6] = v;
    __syncthreads();
    if (t == 0) partials[bid] = (wred[0] + wred[1]) + (wred[2] + wred[3]);
    if (bid < CD) {
        if (t < 240) { curp[t] = 0.0f; nxtp[t] = 0.0f; }
        __syncthreads();
        if (t < SIGLEN) {
            int m = t + 50 - SAMPS * bid;
            curp[t + 50] = (m >= 0 && m < KFILT) ? hA[m] : 0.0f;
        }
        __syncthreads();
        for (int f = 0; f < 2; ++f) {
            const float* h = (f == 0) ? hB : hA;
            if (t < SIGLEN) {
                float a0 = 0.f, a1 = 0.f;
                for (int m = 0; m <= 50; ++m)    a0 = fmaf(h[m], curp[t + 100 - m], a0);
                for (int m = 51; m < KFILT; ++m) a1 = fmaf(h[m], curp[t + 100 - m], a1);
                nxtp[t + 50] = a0 + a1;
            }
            __syncthreads();
            if (t < SIGLEN) curp[t + 50] = nxtp[t + 50];
            __syncthreads();
        }
        if (t < CD) Gd[t * CD + bid] = (float)SAMPS * curp[t * SAMPS + 50];
    }
}

__global__ __launch_bounds__(256) void k2_main(
    const float* __restrict__ enc,
    const float* __restrict__ Wd1, const float* __restrict__ bd1,
    const float* __restrict__ Wd2, const float* __restrict__ bd2,
    const float* __restrict__ noise, const int* __restrict__ snr_p,
    const double* __restrict__ partials, const float* __restrict__ Gd,
    float* __restrict__ out, int B, int NBP)
{
    int t = threadIdx.x, bid = blockIdx.x, base_row = bid * 512;
    __shared__ float  sV1[112], sc1[16], sV2[256], sc2[16];
    __shared__ float  str[2 * MCONST];
    __shared__ float  sG[49];
    __shared__ double wred[4];
    __shared__ float  snz[512 * CD];
    __shared__ float  sinv, ninv;
    sV2[t] = Wd2[t];
    if (t < 112) sV1[t] = Wd1[t];
    if (t < 16)  { sc1[t] = bd1[t]; sc2[t] = bd2[t]; }
    if (t < 49)  sG[t] = Gd[t];
    if (t < MCONST) {
        float ph = (float)(2.0 * 3.14159265358979323846 / (double)MCONST) * (float)t;
        str[t] = cosf(ph); str[MCONST + t] = sinf(ph);
    }
    {
        size_t nb = (size_t)base_row * CD, lim = (size_t)B * CD;
        for (int i = t; i < 512 * CD; i += 256)
            if (nb + i < lim) snz[i] = noise[nb + i];
    }
    {
        double s = 0.0;
        for (int i = t; i < NBP; i += 256) s += partials[i];
        #pragma unroll
        for (int off = 32; off > 0; off >>= 1) s += __shfl_down(s, off);
        if ((t & 63) == 0) wred[t >> 6] = s;
    }
    __syncthreads();
    if (t == 0) sinv = 70.0f / (float)sqrt((wred[0] + wred[1]) + (wred[2] + wred[3]));
    if (t == 1) {
        int iv = *snr_p;
        float sv = (iv >= -1000 && iv <= 1000) ? (float)iv
                                               : *reinterpret_cast<const float*>(snr_p);
        float snr_lin = powf(10.0f, 0.1f * sv);
        ninv = 1.0f / sqrtf((float)(8.0 / 7.0) * snr_lin);
    }
    __syncthreads();
    #pragma unroll
    for (int c = 0; c < 2; ++c) {
        int lrow = c * 256 + t, row = base_row + lrow;
        if (row >= B) continue;
        const float4* ep = reinterpret_cast<const float4*>(enc + (size_t)row * 8);
        float4 e0 = ep[0], e1 = ep[1];
        float ev[7] = {e0.x, e0.y, e0.z, e0.w, e1.x, e1.y, e1.z};
        float sr[CD], si[CD], sgn[CD];
        #pragma unroll
        for (int o = 0; o < CD; ++o) {
            float es = ev[o] * sinv;
            float rv = rintf(es);
            int xi = (int)rv;
            sgn[o] = (xi < 0) ? -1.0f : 1.0f;
            int idx = (xi < 0 ? -xi : xi) & (MCONST - 1);
            sr[o] = str[idx]; si[o] = str[MCONST + idx];
        }
        float res[CD];
        #pragma unroll
        for (int k = 0; k < CD; ++k) {
            float yr = 0.f, yi = 0.f;
            #pragma unroll
            for (int cc = 0; cc < CD; ++cc) {
                float g = sG[k * CD + cc];
                yr = fmaf(g, sr[cc], yr); yi = fmaf(g, si[cc], yi);
            }
            float ang = atan2f(yi, yr);
            float q = ang * (float)(128.0 / (2.0 * 3.14159265358979323846));
            float r = rintf(q);
            float m = (r < 0.0f) ? r + 128.0f : r;
            res[k] = fmaf(snz[lrow * CD + k], ninv, m * sgn[k]);
        }
        float dd[16];
        #pragma unroll
        for (int i = 0; i < 16; ++i) {
            float acc = sc1[i];
            #pragma unroll
            for (int cc = 0; cc < CD; ++cc) acc = fmaf(sV1[i*CD+cc], res[cc], acc);
            dd[i] = (acc >= 0.f) ? acc : 0.01f * acc;
        }
        float4* op = reinterpret_cast<float4*>(out + (size_t)row * IN_DIM);
        #pragma unroll
        for (int q4 = 0; q4 < 4; ++q4) {
            float o0[4];
            #pragma unroll
            for (int u = 0; u < 4; ++u) {
                int i = q4 * 4 + u;
                float acc = sc2[i];
                #pragma unroll
                for (int j = 0; j < 16; ++j) acc = fmaf(sV2[i*16+j], dd[j], acc);
                o0[u] = acc;
            }
            op[q4] = make_float4(o0[0], o0[1], o0[2], o0[3]);
        }
    }
}

// ---------------------------------------------------------------------------
extern "C" void kernel_launch(void* const* d_in, const int* in_sizes, int n_in,
                              void* d_out, int out_size, void* d_ws, size_t ws_size,
                              hipStream_t stream)
{
    const float* x    = (const float*)d_in[0];
    const float* We1  = (const float*)d_in[1];
    const float* be1  = (const float*)d_in[2];
    const float* We2  = (const float*)d_in[3];
    const float* be2  = (const float*)d_in[4];
    const float* Wd1  = (const float*)d_in[5];
    const float* bd1  = (const float*)d_in[6];
    const float* Wd2  = (const float*)d_in[7];
    const float* bd2  = (const float*)d_in[8];
    const float* h_lp = (const float*)d_in[9];
    const float* h_ps = (const float*)d_in[10];
    const float* noise= (const float*)d_in[11];
    const int*   snr  = (const int*)d_in[12];
    float* out = (float*)d_out;

    int B  = in_sizes[0] / IN_DIM;
    int NB = (B + 255) / 256;

    char* ws = (char*)d_ws;

    if (NB <= 512) {
        // zero barrier region [8192, 14592)
        hipMemsetAsync(ws + 8192, 0, 6400, stream);
        k_fused<<<NB, 256, 0, stream>>>(x, We1, be1, We2, be2, Wd1, bd1,
                                        Wd2, bd2, h_lp, h_ps, noise, snr,
                                        ws, out, B, NB);
    } else {
        double* partials = (double*)(ws + 0);
        float*  Gd       = (float*) (ws + 4096);
        float*  enc      = (float*) (ws + 16384);
        int NB2 = (B + 511) / 512;
        k1_enc<<<NB, 256, 0, stream>>>(x, We1, be1, We2, be2, h_lp, h_ps,
                                       enc, partials, Gd, B);
        k2_main<<<NB2, 256, 0, stream>>>(enc, Wd1, bd1, Wd2, bd2, noise, snr,
                                         partials, Gd, out, B, NB);
    }
}

// Round 20
// 25.860 us; speedup vs baseline: 1.2002x; 1.0441x over previous
//
#include <hip/hip_runtime.h>
#include <math.h>

#define IN_DIM   16
#define CD       7
#define SAMPS    20
#define KFILT    101
#define SIGLEN   140      // CD * SAMPS
#define MCONST   128      // 2^CD

// ws layout (bytes):
//   [0     .. 4096)  : double partials[512]          (atomic relaxed agent)
//   [4096  .. 6144)  : float  GR[8][64]  G replicas  (atomic relaxed agent)
//   [8192  .. 14592) : barrier region — memset each launch:
//       L0[g]  u32 @  8192 + g*256  (g<8)   group arrival counters
//       GS[g]  f64 @ 10240 + g*256  (g<8)   group sums
//       ROOT   u32 @ 12288                  root counter
//       FLAG[r]u32 @ 12544 + r*256  (r<8)   release flags; value = norm bits
//   [16384 .. +4.2MB): float enc[B][8]               (fallback path only)

__device__ __forceinline__ unsigned ld_u32(const void* p) {
    return __hip_atomic_load((const unsigned*)p, __ATOMIC_RELAXED,
                             __HIP_MEMORY_SCOPE_AGENT);
}
__device__ __forceinline__ void st_u32(void* p, unsigned v) {
    __hip_atomic_store((unsigned*)p, v, __ATOMIC_RELAXED,
                       __HIP_MEMORY_SCOPE_AGENT);
}
__device__ __forceinline__ unsigned add_u32(void* p) {
    return __hip_atomic_fetch_add((unsigned*)p, 1u, __ATOMIC_RELAXED,
                                  __HIP_MEMORY_SCOPE_AGENT);
}
__device__ __forceinline__ double ld_f64(const void* p) {
    return __hip_atomic_load((const double*)p, __ATOMIC_RELAXED,
                             __HIP_MEMORY_SCOPE_AGENT);
}
__device__ __forceinline__ void st_f64(void* p, double v) {
    __hip_atomic_store((double*)p, v, __ATOMIC_RELAXED,
                       __HIP_MEMORY_SCOPE_AGENT);
}
__device__ __forceinline__ float ld_f32(const void* p) {
    return __hip_atomic_load((const float*)p, __ATOMIC_RELAXED,
                             __HIP_MEMORY_SCOPE_AGENT);
}
__device__ __forceinline__ void st_f32(void* p, float v) {
    __hip_atomic_store((float*)p, v, __ATOMIC_RELAXED,
                       __HIP_MEMORY_SCOPE_AGENT);
}

// ---------------------------------------------------------------------------
// Fused single kernel (grid = NB <= 512, 2 blocks/CU co-resident).
// G straggler halved: stage 3 computed only at the 7 decimation points
// (per-output tap order unchanged -> G bit-identical to r19).
// ---------------------------------------------------------------------------
__global__ __launch_bounds__(256, 2) void k_fused(
    const float* __restrict__ x,
    const float* __restrict__ We1, const float* __restrict__ be1,
    const float* __restrict__ We2, const float* __restrict__ be2,
    const float* __restrict__ Wd1, const float* __restrict__ bd1,
    const float* __restrict__ Wd2, const float* __restrict__ bd2,
    const float* __restrict__ h_lp, const float* __restrict__ h_ps,
    const float* __restrict__ noise, const int* __restrict__ snr_p,
    char* __restrict__ ws, float* __restrict__ out, int B, int NB)
{
    int t   = threadIdx.x;
    int bid = blockIdx.x;
    int row = bid * 256 + t;

    double* partials = (double*)(ws + 0);
    float*  GR       = (float*) (ws + 4096);
    char*   L0       = ws + 8192;
    char*   GS       = ws + 10240;
    char*   ROOT     = ws + 12288;
    char*   FLAG     = ws + 12544;

    __shared__ float4   sW1v[64];               // We1: 16x16 as 64 float4
    __shared__ float4   sW2v[28];               // We2: 7x16  as 28 float4
    __shared__ float4   sV2v[64];               // Wd2: 16x16 as 64 float4
    __shared__ float    sV1[112];               // Wd1: 16x7 (rows misaligned)
    __shared__ float    sb1[16], sb2[7], sc1[16], sc2[16];
    __shared__ float    str[2 * MCONST];
    __shared__ double   wred[4];
    __shared__ float    sG[49];
    __shared__ float    curp[240], nxtp[240];   // [50 pad | 140 | 50 pad]
    __shared__ float    hA[KFILT], hB[KFILT];   // h_ps, h_lp
    __shared__ unsigned sNormBits;
    __shared__ float    ninv;

    // ---------------- phase-1 loads (everything hoisted) ----------------
    if (t < 64) {
        sW1v[t] = reinterpret_cast<const float4*>(We1)[t];
        sV2v[t] = reinterpret_cast<const float4*>(Wd2)[t];
    }
    if (t < 28)  sW2v[t] = reinterpret_cast<const float4*>(We2)[t];
    if (t < 112) sV1[t] = Wd1[t];
    if (t < 16)  { sb1[t] = be1[t]; sc1[t] = bd1[t]; sc2[t] = bd2[t]; }
    if (t < 7)   sb2[t] = be2[t];
    if (bid < CD && t < KFILT) { hA[t] = h_ps[t]; hB[t] = h_lp[t]; }
    if (t < MCONST) {
        float ph = (float)(2.0 * 3.14159265358979323846 / (double)MCONST) * (float)t;
        str[t]          = cosf(ph);
        str[MCONST + t] = sinf(ph);
    }
    __syncthreads();

    // ---------------- encoder (e stays in registers) ----------------
    float e[CD];
    double ss = 0.0;
    if (row < B) {
        const float4* xp = reinterpret_cast<const float4*>(x + (size_t)row * IN_DIM);
        float4 v0 = xp[0], v1 = xp[1], v2 = xp[2], v3 = xp[3];
        float h[16];
        #pragma unroll
        for (int i = 0; i < 16; ++i) {
            float4 w0 = sW1v[i*4+0], w1 = sW1v[i*4+1],
                   w2 = sW1v[i*4+2], w3 = sW1v[i*4+3];
            float acc = sb1[i];
            acc = fmaf(w0.x, v0.x, acc); acc = fmaf(w0.y, v0.y, acc);
            acc = fmaf(w0.z, v0.z, acc); acc = fmaf(w0.w, v0.w, acc);
            acc = fmaf(w1.x, v1.x, acc); acc = fmaf(w1.y, v1.y, acc);
            acc = fmaf(w1.z, v1.z, acc); acc = fmaf(w1.w, v1.w, acc);
            acc = fmaf(w2.x, v2.x, acc); acc = fmaf(w2.y, v2.y, acc);
            acc = fmaf(w2.z, v2.z, acc); acc = fmaf(w2.w, v2.w, acc);
            acc = fmaf(w3.x, v3.x, acc); acc = fmaf(w3.y, v3.y, acc);
            acc = fmaf(w3.z, v3.w == v3.w ? v3.w : v3.w, acc); // placeholder never taken
            acc = fmaf(w3.z, v3.z, acc) - fmaf(w3.z, v3.z, 0.f) + fmaf(w3.z, v3.z, 0.f);
            h[i] = acc;
        }
        // NOTE: the two lines above would break bit-exactness — replaced by
        // the correct straightforward form below (kept: see loop).
        #pragma unroll
        for (int i = 0; i < 16; ++i) {
            float4 w0 = sW1v[i*4+0], w1 = sW1v[i*4+1],
                   w2 = sW1v[i*4+2], w3 = sW1v[i*4+3];
            float acc = sb1[i];
            acc = fmaf(w0.x, v0.x, acc); acc = fmaf(w0.y, v0.y, acc);
            acc = fmaf(w0.z, v0.z, acc); acc = fmaf(w0.w, v0.w, acc);
            acc = fmaf(w1.x, v1.x, acc); acc = fmaf(w1.y, v1.y, acc);
            acc = fmaf(w1.z, v1.z, acc); acc = fmaf(w1.w, v1.w, acc);
            acc = fmaf(w2.x, v2.x, acc); acc = fmaf(w2.y, v2.y, acc);
            acc = fmaf(w2.z, v2.z, acc); acc = fmaf(w2.w, v2.w, acc);
            acc = fmaf(w3.x, v3.x, acc); acc = fmaf(w3.y, v3.y, acc);
            acc = fmaf(w3.z, v3.z, acc); acc = fmaf(w3.w, v3.w, acc);
            h[i] = (acc >= 0.f) ? acc : 0.01f * acc;
        }
        #pragma unroll
        for (int o = 0; o < CD; ++o) {
            float4 w0 = sW2v[o*4+0], w1 = sW2v[o*4+1],
                   w2 = sW2v[o*4+2], w3 = sW2v[o*4+3];
            float acc = sb2[o];
            acc = fmaf(w0.x, h[0],  acc); acc = fmaf(w0.y, h[1],  acc);
            acc = fmaf(w0.z, h[2],  acc); acc = fmaf(w0.w, h[3],  acc);
            acc = fmaf(w1.x, h[4],  acc); acc = fmaf(w1.y, h[5],  acc);
            acc = fmaf(w1.z, h[6],  acc); acc = fmaf(w1.w, h[7],  acc);
            acc = fmaf(w2.x, h[8],  acc); acc = fmaf(w2.y, h[9],  acc);
            acc = fmaf(w2.z, h[10], acc); acc = fmaf(w2.w, h[11], acc);
            acc = fmaf(w3.x, h[12], acc); acc = fmaf(w3.y, h[13], acc);
            acc = fmaf(w3.z, h[14], acc); acc = fmaf(w3.w, h[15], acc);
            e[o] = acc;
            ss += (double)acc * (double)acc;
        }
    }
    // wave shfl reduce (f64), one barrier; store partial (wave-0 global store)
    double v = ss;
    #pragma unroll
    for (int off = 32; off > 0; off >>= 1) v += __shfl_down(v, off);
    if ((t & 63) == 0) wred[t >> 6] = v;
    __syncthreads();
    if (t == 0) st_f64(&partials[bid], (wred[0] + wred[1]) + (wred[2] + wred[3]));

    // ---------------- G column (blocks 0..6), f32, -> 8 replicas ----------
    // stage1 = shifted h_ps (free); stage2 = conv h_lp (full 140);
    // stage3 = conv h_ps evaluated ONLY at the 7 decimation points.
    if (bid < CD) {
        if (t < 240) { curp[t] = 0.0f; nxtp[t] = 0.0f; }
        __syncthreads();
        if (t < SIGLEN) {
            int m = t + 50 - SAMPS * bid;    // conv(delta, h_ps) = shifted h_ps
            curp[t + 50] = (m >= 0 && m < KFILT) ? hA[m] : 0.0f;
        }
        __syncthreads();
        if (t < SIGLEN) {                    // stage 2: h_lp, all 140 outputs
            float a0 = 0.f, a1 = 0.f;
            for (int m = 0; m <= 50; ++m)    a0 = fmaf(hB[m], curp[t + 100 - m], a0);
            for (int m = 51; m < KFILT; ++m) a1 = fmaf(hB[m], curp[t + 100 - m], a1);
            nxtp[t + 50] = a0 + a1;
        }
        __syncthreads();
        if (t < CD) {                        // stage 3: h_ps at positions 20*t
            int p = t * SAMPS;
            float a0 = 0.f, a1 = 0.f;        // same per-output tap order as r19
            for (int m = 0; m <= 50; ++m)    a0 = fmaf(hA[m], nxtp[p + 100 - m], a0);
            for (int m = 51; m < KFILT; ++m) a1 = fmaf(hA[m], nxtp[p + 100 - m], a1);
            float gv = (float)SAMPS * (a0 + a1);
            #pragma unroll
            for (int r = 0; r < 8; ++r)      // wave-0 lanes 0..6 -> 8 replicas
                st_f32(&GR[r * 64 + t * CD + bid], gv);
        }
    }

    // ---------------- pre-barrier hoisted work ----------------
    // noise prefetched straight into registers; latency hides under barrier
    float nz[CD];
    if (row < B) {
        const float* np0 = noise + (size_t)row * CD;
        #pragma unroll
        for (int k = 0; k < CD; ++k) nz[k] = np0[k];
    } else {
        #pragma unroll
        for (int k = 0; k < CD; ++k) nz[k] = 0.f;
    }
    if (t == 1) {
        int iv = *snr_p;
        float sv = (iv >= -1000 && iv <= 1000) ? (float)iv
                                               : *reinterpret_cast<const float*>(snr_p);
        float snr_lin = powf(10.0f, 0.1f * sv);
        ninv = 1.0f / sqrtf((float)(8.0 / 7.0) * snr_lin);  // 1/sqrt(2*rate*snr)
    }

    // ---------------- barrier: tree arrival, wave-parallel reduce,
    //                  flag carries norm bits ----------------
    __syncthreads();          // all waves done; all global stores were wave-0's
    if (t < 64) {
        asm volatile("s_waitcnt vmcnt(0)" ::: "memory");  // wave-0 stores at LLC
        int g       = bid >> 6;
        int gbase   = g << 6;
        int gsize   = (NB - gbase < 64) ? (NB - gbase) : 64;
        int ngroups = (NB + 63) >> 6;

        unsigned aret = 0;
        if (t == 0) aret = add_u32(L0 + (size_t)g * 256);
        aret = __shfl(aret, 0);
        if ((int)aret == gsize - 1) {
            // group-last: WAVE-PARALLEL reduce of this group's partials
            double p = (t < gsize) ? ld_f64(&partials[gbase + t]) : 0.0;
            #pragma unroll
            for (int off = 32; off > 0; off >>= 1) p += __shfl_down(p, off);
            unsigned rret = 0;
            if (t == 0) {
                st_f64(GS + (size_t)g * 256, p);
                asm volatile("s_waitcnt vmcnt(0)" ::: "memory");
                rret = add_u32(ROOT);
            }
            rret = __shfl(rret, 0);
            if ((int)rret == ngroups - 1) {
                // root-last: wave-parallel reduce of group sums -> norm
                double gsv = (t < ngroups) ? ld_f64(GS + (size_t)t * 256) : 0.0;
                #pragma unroll
                for (int off = 32; off > 0; off >>= 1) gsv += __shfl_down(gsv, off);
                unsigned bits = 0;
                if (t == 0) bits = __float_as_uint((float)sqrt(gsv));
                bits = __shfl(bits, 0);
                if (t < 8) st_u32(FLAG + (size_t)t * 256, bits);
            }
        }
        // release: poll own flag replica; its VALUE is the norm
        if (t == 0) {
            unsigned b2;
            while ((b2 = ld_u32(FLAG + (size_t)(bid & 7) * 256)) == 0u)
                __builtin_amdgcn_s_sleep(2);
            sNormBits = b2;
        }
        // after release, G replicas are globally visible: fetch ours
        if (t < 49) sG[t] = ld_f32(&GR[(size_t)(bid & 7) * 64 + t]);
    }
    __syncthreads();
    float sinv = 70.0f / __uint_as_float(sNormBits);

    // ---------------- phase 2 ----------------
    if (row >= B) return;

    float sr[CD], si[CD], sgn[CD], fidx[CD];
    #pragma unroll
    for (int o = 0; o < CD; ++o) {
        float es = e[o] * sinv;                  // enc * (70/||enc||)
        float rv = rintf(es);                    // jnp.round = half-to-even
        int xi = (int)rv;
        sgn[o] = (xi < 0) ? -1.0f : 1.0f;
        int idx = (xi < 0 ? -xi : xi) & (MCONST - 1);   // mod(|xi|, 128)
        fidx[o] = (float)idx;
        sr[o] = str[idx];
        si[o] = str[MCONST + idx];
    }

    const float QSC = 20.37183271576260f;        // 128 / (2*pi)
    float res[CD];
    #pragma unroll
    for (int k = 0; k < CD; ++k) {
        float yr = 0.f, yi = 0.f;
        #pragma unroll
        for (int cc = 0; cc < CD; ++cc) {
            float g = sG[k * CD + cc];
            yr = fmaf(g, sr[cc], yr);
            yi = fmaf(g, si[cc], yi);
        }
        // rotate by conj(transmitted symbol k): ang = phi_idx + atan2(b, a)
        float c = sr[k], s = si[k];
        float a = fmaf(yr, c, yi * s);           // yr*c + yi*s
        float b = fmaf(yi, c, -(yr * s));        // yi*c - yr*s
        float q;
        if (fabsf(b) < 0.25f * a) {              // small-angle & a>0: poly atan
            float u  = b / a;
            float u2 = u * u;
            float w  = fmaf(u2, -0.142857143f, 0.2f);     // -1/7, +1/5
            w        = fmaf(u2, w, -0.333333333f);        // -1/3
            w        = fmaf(u2, w, 1.0f);
            q = fmaf(u * w, QSC, fidx[k]);
        } else {                                 // rare: exact fallback
            q = fmaf(atan2f(b, a), QSC, fidx[k]);
        }
        float r = rintf(q);                      // q in [-64, 191]
        if (r < 0.0f) r += 128.0f;
        else if (r >= 128.0f) r -= 128.0f;       // jnp.mod semantics
        res[k] = fmaf(nz[k], ninv, r * sgn[k]);
    }

    float dd[16];
    #pragma unroll
    for (int i = 0; i < 16; ++i) {
        float acc = sc1[i];
        #pragma unroll
        for (int cc = 0; cc < CD; ++cc) acc = fmaf(sV1[i*CD+cc], res[cc], acc);
        dd[i] = (acc >= 0.f) ? acc : 0.01f * acc;
    }
    float4* op = reinterpret_cast<float4*>(out + (size_t)row * IN_DIM);
    #pragma unroll
    for (int q4 = 0; q4 < 4; ++q4) {
        float o0[4];
        #pragma unroll
        for (int u = 0; u < 4; ++u) {
            int i = q4 * 4 + u;
            float4 w0 = sV2v[i*4+0], w1 = sV2v[i*4+1],
                   w2 = sV2v[i*4+2], w3 = sV2v[i*4+3];
            float acc = sc2[i];
            acc = fmaf(w0.x, dd[0],  acc); acc = fmaf(w0.y, dd[1],  acc);
            acc = fmaf(w0.z, dd[2],  acc); acc = fmaf(w0.w, dd[3],  acc);
            acc = fmaf(w1.x, dd[4],  acc); acc = fmaf(w1.y, dd[5],  acc);
            acc = fmaf(w1.z, dd[6],  acc); acc = fmaf(w1.w, dd[7],  acc);
            acc = fmaf(w2.x, dd[8],  acc); acc = fmaf(w2.y, dd[9],  acc);
            acc = fmaf(w2.z, dd[10], acc); acc = fmaf(w2.w, dd[11], acc);
            acc = fmaf(w3.x, dd[12], acc); acc = fmaf(w3.y, dd[13], acc);
            acc = fmaf(w3.z, dd[14], acc); acc = fmaf(w3.w, dd[15], acc);
            o0[u] = acc;
        }
        op[q4] = make_float4(o0[0], o0[1], o0[2], o0[3]);
    }
}

// ---------------------------------------------------------------------------
// Fallback 2-kernel path (r14, proven) for NB > 512
// ---------------------------------------------------------------------------
__global__ __launch_bounds__(256) void k1_enc(
    const float* __restrict__ x,
    const float* __restrict__ We1, const float* __restrict__ be1,
    const float* __restrict__ We2, const float* __restrict__ be2,
    const float* __restrict__ h_lp, const float* __restrict__ h_ps,
    float* __restrict__ enc, double* __restrict__ partials,
    float* __restrict__ Gd, int B)
{
    int t = threadIdx.x, bid = blockIdx.x, row = bid * 256 + t;
    __shared__ float  sW1[256], sW2[112], sb1[16], sb2[7];
    __shared__ double wred[4];
    __shared__ float  curp[240], nxtp[240];
    __shared__ float  hA[KFILT], hB[KFILT];
    sW1[t] = We1[t];
    if (t < 112) sW2[t] = We2[t];
    if (t < 16)  sb1[t] = be1[t];
    if (t < 7)   sb2[t] = be2[t];
    if (bid < CD && t < KFILT) { hA[t] = h_ps[t]; hB[t] = h_lp[t]; }
    __syncthreads();
    double ss = 0.0;
    if (row < B) {
        const float4* xp = reinterpret_cast<const float4*>(x + (size_t)row * IN_DIM);
        float4 v0 = xp[0], v1 = xp[1], v2 = xp[2], v3 = xp[3];
        float xr[16] = {v0.x,v0.y,v0.z,v0.w, v1.x,v1.y,v1.z,v1.w,
                        v2.x,v2.y,v2.z,v2.w, v3.x,v3.y,v3.z,v3.w};
        float h[16];
        #pragma unroll
        for (int i = 0; i < 16; ++i) {
            float acc = sb1[i];
            #pragma unroll
            for (int j = 0; j < 16; ++j) acc = fmaf(sW1[i*16+j], xr[j], acc);
            h[i] = (acc >= 0.f) ? acc : 0.01f * acc;
        }
        float e[8];
        #pragma unroll
        for (int o = 0; o < CD; ++o) {
            float acc = sb2[o];
            #pragma unroll
            for (int i = 0; i < 16; ++i) acc = fmaf(sW2[o*16+i], h[i], acc);
            e[o] = acc; ss += (double)acc * (double)acc;
        }
        e[7] = 0.f;
        float4* ep = reinterpret_cast<float4*>(enc + (size_t)row * 8);
        ep[0] = make_float4(e[0], e[1], e[2], e[3]);
        ep[1] = make_float4(e[4], e[5], e[6], e[7]);
    }
    double v = ss;
    #pragma unroll
    for (int off = 32; off > 0; off >>= 1) v += __shfl_down(v, off);
    if ((t & 63) == 0) wred[t >> 6] = v;
    __syncthreads();
    if (t == 0) partials[bid] = (wred[0] + wred[1]) + (wred[2] + wred[3]);
    if (bid < CD) {
        if (t < 240) { curp[t] = 0.0f; nxtp[t] = 0.0f; }
        __syncthreads();
        if (t < SIGLEN) {
            int m = t + 50 - SAMPS * bid;
            curp[t + 50] = (m >= 0 && m < KFILT) ? hA[m] : 0.0f;
        }
        __syncthreads();
        if (t < SIGLEN) {
            float a0 = 0.f, a1 = 0.f;
            for (int m = 0; m <= 50; ++m)    a0 = fmaf(hB[m], curp[t + 100 - m], a0);
            for (int m = 51; m < KFILT; ++m) a1 = fmaf(hB[m], curp[t + 100 - m], a1);
            nxtp[t + 50] = a0 + a1;
        }
        __syncthreads();
        if (t < CD) {
            int p = t * SAMPS;
            float a0 = 0.f, a1 = 0.f;
            for (int m = 0; m <= 50; ++m)    a0 = fmaf(hA[m], nxtp[p + 100 - m], a0);
            for (int m = 51; m < KFILT; ++m) a1 = fmaf(hA[m], nxtp[p + 100 - m], a1);
            Gd[t * CD + bid] = (float)SAMPS * (a0 + a1);
        }
    }
}

__global__ __launch_bounds__(256) void k2_main(
    const float* __restrict__ enc,
    const float* __restrict__ Wd1, const float* __restrict__ bd1,
    const float* __restrict__ Wd2, const float* __restrict__ bd2,
    const float* __restrict__ noise, const int* __restrict__ snr_p,
    const double* __restrict__ partials, const float* __restrict__ Gd,
    float* __restrict__ out, int B, int NBP)
{
    int t = threadIdx.x, bid = blockIdx.x, base_row = bid * 512;
    __shared__ float  sV1[112], sc1[16], sV2[256], sc2[16];
    __shared__ float  str[2 * MCONST];
    __shared__ float  sG[49];
    __shared__ double wred[4];
    __shared__ float  snz[512 * CD];
    __shared__ float  sinv, ninv;
    sV2[t] = Wd2[t];
    if (t < 112) sV1[t] = Wd1[t];
    if (t < 16)  { sc1[t] = bd1[t]; sc2[t] = bd2[t]; }
    if (t < 49)  sG[t] = Gd[t];
    if (t < MCONST) {
        float ph = (float)(2.0 * 3.14159265358979323846 / (double)MCONST) * (float)t;
        str[t] = cosf(ph); str[MCONST + t] = sinf(ph);
    }
    {
        size_t nb = (size_t)base_row * CD, lim = (size_t)B * CD;
        for (int i = t; i < 512 * CD; i += 256)
            if (nb + i < lim) snz[i] = noise[nb + i];
    }
    {
        double s = 0.0;
        for (int i = t; i < NBP; i += 256) s += partials[i];
        #pragma unroll
        for (int off = 32; off > 0; off >>= 1) s += __shfl_down(s, off);
        if ((t & 63) == 0) wred[t >> 6] = s;
    }
    __syncthreads();
    if (t == 0) sinv = 70.0f / (float)sqrt((wred[0] + wred[1]) + (wred[2] + wred[3]));
    if (t == 1) {
        int iv = *snr_p;
        float sv = (iv >= -1000 && iv <= 1000) ? (float)iv
                                               : *reinterpret_cast<const float*>(snr_p);
        float snr_lin = powf(10.0f, 0.1f * sv);
        ninv = 1.0f / sqrtf((float)(8.0 / 7.0) * snr_lin);
    }
    __syncthreads();
    #pragma unroll
    for (int c = 0; c < 2; ++c) {
        int lrow = c * 256 + t, row = base_row + lrow;
        if (row >= B) continue;
        const float4* ep = reinterpret_cast<const float4*>(enc + (size_t)row * 8);
        float4 e0 = ep[0], e1 = ep[1];
        float ev[7] = {e0.x, e0.y, e0.z, e0.w, e1.x, e1.y, e1.z};
        float sr[CD], si[CD], sgn[CD];
        #pragma unroll
        for (int o = 0; o < CD; ++o) {
            float es = ev[o] * sinv;
            float rv = rintf(es);
            int xi = (int)rv;
            sgn[o] = (xi < 0) ? -1.0f : 1.0f;
            int idx = (xi < 0 ? -xi : xi) & (MCONST - 1);
            sr[o] = str[idx]; si[o] = str[MCONST + idx];
        }
        float res[CD];
        #pragma unroll
        for (int k = 0; k < CD; ++k) {
            float yr = 0.f, yi = 0.f;
            #pragma unroll
            for (int cc = 0; cc < CD; ++cc) {
                float g = sG[k * CD + cc];
                yr = fmaf(g, sr[cc], yr); yi = fmaf(g, si[cc], yi);
            }
            float ang = atan2f(yi, yr);
            float q = ang * (float)(128.0 / (2.0 * 3.14159265358979323846));
            float r = rintf(q);
            float m = (r < 0.0f) ? r + 128.0f : r;
            res[k] = fmaf(snz[lrow * CD + k], ninv, m * sgn[k]);
        }
        float dd[16];
        #pragma unroll
        for (int i = 0; i < 16; ++i) {
            float acc = sc1[i];
            #pragma unroll
            for (int cc = 0; cc < CD; ++cc) acc = fmaf(sV1[i*CD+cc], res[cc], acc);
            dd[i] = (acc >= 0.f) ? acc : 0.01f * acc;
        }
        float4* op = reinterpret_cast<float4*>(out + (size_t)row * IN_DIM);
        #pragma unroll
        for (int q4 = 0; q4 < 4; ++q4) {
            float o0[4];
            #pragma unroll
            for (int u = 0; u < 4; ++u) {
                int i = q4 * 4 + u;
                float acc = sc2[i];
                #pragma unroll
                for (int j = 0; j < 16; ++j) acc = fmaf(sV2[i*16+j], dd[j], acc);
                o0[u] = acc;
            }
            op[q4] = make_float4(o0[0], o0[1], o0[2], o0[3]);
        }
    }
}

// ---------------------------------------------------------------------------
extern "C" void kernel_launch(void* const* d_in, const int* in_sizes, int n_in,
                              void* d_out, int out_size, void* d_ws, size_t ws_size,
                              hipStream_t stream)
{
    const float* x    = (const float*)d_in[0];
    const float* We1  = (const float*)d_in[1];
    const float* be1  = (const float*)d_in[2];
    const float* We2  = (const float*)d_in[3];
    const float* be2  = (const float*)d_in[4];
    const float* Wd1  = (const float*)d_in[5];
    const float* bd1  = (const float*)d_in[6];
    const float* Wd2  = (const float*)d_in[7];
    const float* bd2  = (const float*)d_in[8];
    const float* h_lp = (const float*)d_in[9];
    const float* h_ps = (const float*)d_in[10];
    const float* noise= (const float*)d_in[11];
    const int*   snr  = (const int*)d_in[12];
    float* out = (float*)d_out;

    int B  = in_sizes[0] / IN_DIM;
    int NB = (B + 255) / 256;

    char* ws = (char*)d_ws;

    if (NB <= 512) {
        // zero barrier region [8192, 14592)
        hipMemsetAsync(ws + 8192, 0, 6400, stream);
        k_fused<<<NB, 256, 0, stream>>>(x, We1, be1, We2, be2, Wd1, bd1,
                                        Wd2, bd2, h_lp, h_ps, noise, snr,
                                        ws, out, B, NB);
    } else {
        double* partials = (double*)(ws + 0);
        float*  Gd       = (float*) (ws + 4096);
        float*  enc      = (float*) (ws + 16384);
        int NB2 = (B + 511) / 512;
        k1_enc<<<NB, 256, 0, stream>>>(x, We1, be1, We2, be2, h_lp, h_ps,
                                       enc, partials, Gd, B);
        k2_main<<<NB2, 256, 0, stream>>>(enc, Wd1, bd1, Wd2, bd2, noise, snr,
                                         partials, Gd, out, B, NB);
    }
}